// Round 6
// baseline (2237.990 us; speedup 1.0000x reference)
//
#include <hip/hip_runtime.h>
#include <math.h>

#define NN_ 128   // batch
#define TT  100   // time steps
#define SS  128   // state dim
#define AA  32    // action dim
#define LL  1024  // hidden (= Z)
#define NBLK 256  // 4 groups x 64 matmul blocks (64 slots = exactly one poll wave)
#define HRS  1034 // LDS h-stage row stride (bf16): max 2-way bank aliasing (free)

// Round-6: barrier v4 (RMW-free direct poll). Arrive = one agent store of gen
// into the block's private slot. Wait = wave 0 reads the group's 64 slots with
// ONE coalesced 256B load (lane l -> slot l) and ballots (v < gen) == 0.
// No fetch_add, no master, no flag line, no fan-out. All cross-block ops are
// proven-coherent classes: __hip_atomic_* AGENT + asm "sc0 sc1".

typedef __attribute__((ext_vector_type(8))) short bf16x8;   // 8 bf16 in 4 VGPRs
typedef __attribute__((ext_vector_type(4))) float f32x4;
typedef __attribute__((ext_vector_type(4))) int   i32x4;

__device__ __forceinline__ float sigmoidf_(float x) { return 1.0f / (1.0f + expf(-x)); }
__device__ __forceinline__ unsigned short f2bf(float x) {
    union { float f; unsigned u; } v; v.f = x;
    return (unsigned short)((v.u + 0x7fffu + ((v.u >> 16) & 1u)) >> 16);   // RNE
}

// ---- coherent access helpers (system scope: sc0 sc1) -----------------------
__device__ __forceinline__ i32x4 ldg16(const unsigned short* p) {
    i32x4 r; asm volatile("global_load_dwordx4 %0, %1, off sc0 sc1"
                          : "=&v"(r) : "v"((unsigned long long)p));
    return r;   // caller must s_waitcnt vmcnt(0) before use
}
__device__ __forceinline__ void stg16(unsigned short* p, bf16x8 v) {
    union { bf16x8 h; i32x4 i; } u; u.h = v;
    asm volatile("global_store_dwordx4 %0, %1, off sc0 sc1"
                 :: "v"((unsigned long long)p), "v"(u.i) : "memory");
}
__device__ __forceinline__ void st2(unsigned short* p, unsigned short v) {
    asm volatile("global_store_short %0, %1, off sc0 sc1"
                 :: "v"((unsigned long long)p), "v"((unsigned)v) : "memory");
}
__device__ __forceinline__ int aload(const int* p) {
    return __hip_atomic_load(p, __ATOMIC_RELAXED, __HIP_MEMORY_SCOPE_AGENT);
}
__device__ __forceinline__ void astore(int* p, int v) {
    __hip_atomic_store(p, v, __ATOMIC_RELAXED, __HIP_MEMORY_SCOPE_AGENT);
}

struct PParams {
    const float *s, *a, *s_next, *eps;
    const float *eWih, *eWhh, *ebih, *ebhh;
    const float *muW, *mub, *lvW, *lvb;
    const float *dWih, *dWhh, *dbih, *dbhh;
    const float *d1W, *d1b, *d2W, *d2b, *d3W, *d3b;
    int *bar;
    int *endv, *startv, *limitv;
    unsigned short *hencAb, *hencBb, *hdecAb, *hdecBb, *hf_bf;
    unsigned short *eWih_b, *eWhh_b, *dWih_b, *dWhh_b, *mlW_b, *xenc_b, *adec_b;
    unsigned short *d1Wb, *d2Wb, *d3Wb;
    float *loss;
};

// ---------------------------------------------------------------- h-tile stage
// 32 rows (permuted) x 1024 cols bf16 (64 KB): 16 x 16B loads per thread.
__device__ __forceinline__ void stage_h32p(const unsigned short* __restrict__ src,
                                           const int* __restrict__ sperm,
                                           unsigned short* hstage, int tid) {
    i32x4 v[16];
    const int p = tid >> 7, col = (tid & 127) * 8;
    #pragma unroll
    for (int k = 0; k < 16; ++k) {
        const int row = sperm[p + 2 * k];           // physical sample id
        v[k] = ldg16(src + (size_t)row * LL + col);
    }
    asm volatile("s_waitcnt vmcnt(0)" ::: "memory");
    #pragma unroll
    for (int k = 0; k < 16; ++k)
        *(i32x4*)&hstage[(p + 2 * k) * HRS + col] = v[k];
}

// ---------------------------------------------------------------- barriers
// Global (phase 0 only): bar[g8*16] 8 class counters (32 each); [128] master;
// [132] broken; [144+b*16] per-block flags.
__device__ void gbar_global(int* bar, int bid, int tid, int gen) {
    __syncthreads();
    if (tid == 0) {
        if (aload(bar + 132) == 0) {
            const int g8 = bid & 7;
            int pos = __hip_atomic_fetch_add(bar + g8 * 16, 1, __ATOMIC_RELAXED, __HIP_MEMORY_SCOPE_AGENT);
            if (pos + 1 == (NBLK / 8) * gen) {
                int mp = __hip_atomic_fetch_add(bar + 128, 1, __ATOMIC_RELAXED, __HIP_MEMORY_SCOPE_AGENT);
                if (mp + 1 == 8 * gen) {
                    for (int b = 0; b < NBLK; ++b)
                        astore(bar + 144 + b * 16, gen);
                }
            }
            int it = 0;
            while (aload(bar + 144 + bid * 16) < gen) {
                __builtin_amdgcn_s_sleep(1);
                if (++it > 4000000) { astore(bar + 132, 1); break; }
            }
        }
    }
    __syncthreads();
}

// Group per-step barrier v4 (direct poll, RMW-free).
//   slots = bar + 4608 + g*256 : 64 ints, one per block (256B region).
// Arrive: tid0 stores gen into slots[lbid]. Wait: wave 0, lane l polls
// slots[l] (coalesced 256B), done when ballot(v < gen) == 0.
__device__ void gbar4(int* slots, int* brk, int lbid, int tid, int gen, int* sbrk) {
    asm volatile("s_waitcnt vmcnt(0)" ::: "memory");   // drain this wave's h stores
    __syncthreads();
    if (tid == 0) astore(slots + lbid, gen);
    if (tid < 64) {
        if (*sbrk == 0) {
            int it = 0;
            for (;;) {
                int v = aload(slots + tid);
                if (__ballot(v < gen) == 0ull) break;
                __builtin_amdgcn_s_sleep(1);
                if (((++it) & 2047) == 0) {
                    int bv = 0;
                    if (tid == 0) bv = aload(brk);
                    bv = __shfl(bv, 0);
                    if (bv) { if (tid == 0) *sbrk = 1; break; }
                    if (it > 2000000) {
                        if (tid == 0) { astore(brk, 1); *sbrk = 1; }
                        break;
                    }
                }
            }
        }
    }
    __syncthreads();
}

// ---------------------------------------------------------------- init (separate launch)
__global__ void init_kernel(int* bar, float* loss) {
    for (int i = threadIdx.x; i < 5632; i += 256) bar[i] = 0;
    if (threadIdx.x == 0) loss[0] = 0.0f;
}

// ---------------------------------------------------------------- GRU step matmul tile
// Per group: 64 blocks x 16 j-cols (3 gates), 32 samples (permuted via sperm).
// Waves: nh=w&1 sample-half, kh=w>>1 K-half. fp32 h state lives in `hold` regs
// of kh==0 waves; h stores coalesced 16B system-scope via LDS transpose.
// trb = transpose scratch in shu (NOT hstage: head reads hstage afterwards).
template<int XK, bool IS_DEC>
__device__ void gru_tile(const int* __restrict__ sperm, const int jb, const int tid,
    const unsigned short* __restrict__ h_bf, unsigned short* __restrict__ ho_bf,
    const unsigned short* __restrict__ Whh_b, const unsigned short* __restrict__ Wih_b,
    const unsigned short* __restrict__ x_bf,
    const float* __restrict__ bih, const float* __restrict__ bhh,
    const int* __restrict__ endv, unsigned short* __restrict__ hf_bf,
    int t, f32x4 (&red)[2][4][64], unsigned short* hstage, unsigned short* trb,
    f32x4& hold)
{
    const int lane = tid & 63, w = tid >> 6;
    const int nh = w & 1, kh = w >> 1;
    const int m = lane & 15, quad = lane >> 4;
    const int jcol = jb + m;

    stage_h32p(h_bf, sperm, hstage, tid);
    __syncthreads();

    f32x4 accr{}, accz{}, acchn{}, accxn{};

    {   // hidden: K = 1024, 32 chunks, split 16/16 across kh; A from LDS
        const int arow = (nh * 16 + m) * HRS + quad * 8;
        const unsigned short* brp = Whh_b + (size_t)(0 * LL + jcol) * LL + quad * 8;
        const unsigned short* bzp = Whh_b + (size_t)(1 * LL + jcol) * LL + quad * 8;
        const unsigned short* bnp = Whh_b + (size_t)(2 * LL + jcol) * LL + quad * 8;
        #pragma unroll 4
        for (int c = kh * 16; c < kh * 16 + 16; ++c) {
            const int k0 = c * 32;
            bf16x8 av = *(const bf16x8*)&hstage[arow + k0];
            bf16x8 br = *(const bf16x8*)(brp + k0);
            bf16x8 bz = *(const bf16x8*)(bzp + k0);
            bf16x8 bn = *(const bf16x8*)(bnp + k0);
            accr  = __builtin_amdgcn_mfma_f32_16x16x32_bf16(av, br, accr, 0, 0, 0);
            accz  = __builtin_amdgcn_mfma_f32_16x16x32_bf16(av, bz, accz, 0, 0, 0);
            acchn = __builtin_amdgcn_mfma_f32_16x16x32_bf16(av, bn, acchn, 0, 0, 0);
        }
    }
    {   // input: K = XK (enc 160, dec 32); read-only -> plain L1/L2-cached loads
        const int XC = XK / 32, XC0 = (XC + 1) / 2;
        const size_t xstride = IS_DEC ? (size_t)(50 * AA) : (size_t)(TT * (SS + AA));
        const int nphys = sperm[nh * 16 + m];
        const unsigned short* xp  = x_bf + (size_t)nphys * xstride + (size_t)t * XK + quad * 8;
        const unsigned short* brp = Wih_b + (size_t)(0 * LL + jcol) * XK + quad * 8;
        const unsigned short* bzp = Wih_b + (size_t)(1 * LL + jcol) * XK + quad * 8;
        const unsigned short* bnp = Wih_b + (size_t)(2 * LL + jcol) * XK + quad * 8;
        #pragma unroll
        for (int c = (kh ? XC0 : 0); c < (kh ? XC : XC0); ++c) {
            const int k0 = c * 32;
            bf16x8 av = *(const bf16x8*)(xp + k0);
            bf16x8 br = *(const bf16x8*)(brp + k0);
            bf16x8 bz = *(const bf16x8*)(bzp + k0);
            bf16x8 bn = *(const bf16x8*)(bnp + k0);
            accr  = __builtin_amdgcn_mfma_f32_16x16x32_bf16(av, br, accr, 0, 0, 0);
            accz  = __builtin_amdgcn_mfma_f32_16x16x32_bf16(av, bz, accz, 0, 0, 0);
            accxn = __builtin_amdgcn_mfma_f32_16x16x32_bf16(av, bn, accxn, 0, 0, 0);
        }
    }
    if (kh == 1) {
        red[nh][0][lane] = accr;  red[nh][1][lane] = accz;
        red[nh][2][lane] = acchn; red[nh][3][lane] = accxn;
    }
    __syncthreads();
    if (kh == 0) {
        accr  += red[nh][0][lane];  accz  += red[nh][1][lane];
        acchn += red[nh][2][lane];  accxn += red[nh][3][lane];
        const float br_  = bih[jcol] + bhh[jcol];
        const float bz_  = bih[LL + jcol] + bhh[LL + jcol];
        const float bxn_ = bih[2 * LL + jcol];
        const float bhn_ = bhh[2 * LL + jcol];
        unsigned short* tr = trb + nh * (16 * 24);       // wave-private transpose scratch
        #pragma unroll
        for (int i = 0; i < 4; ++i) {
            const int n = sperm[nh * 16 + quad * 4 + i]; // C layout: row=quad*4+i, col=m
            float r = sigmoidf_(accr[i] + br_);
            float z = sigmoidf_(accz[i] + bz_);
            float g = tanhf(accxn[i] + bxn_ + r * (acchn[i] + bhn_));
            float hn = (1.0f - z) * g + z * hold[i];
            hold[i] = hn;
            unsigned short hb = f2bf(hn);
            tr[(quad * 4 + i) * 24 + m] = hb;            // LDS transpose (wave-lockstep)
            if (!IS_DEC) { if (endv[n] == t) st2(hf_bf + (size_t)n * LL + jcol, hb); }
        }
        // coalesced 16B n-major stores: lanes 0..31 each store 8 bf16
        if (lane < 32) {
            const int nl = lane >> 1, jh = lane & 1;
            bf16x8 vv = *(const bf16x8*)&tr[nl * 24 + jh * 8];
            stg16(ho_bf + (size_t)sperm[nh * 16 + nl] * LL + jb + jh * 8, vv);
        }
    }
}

// ---------------------------------------------------------------- reparametrize tile
__device__ void emb_tile(const PParams& P, const int* __restrict__ sperm, const int jb,
                         const int tid, f32x4 (&red)[2][4][64], unsigned short* hstage,
                         unsigned short* trb, f32x4& hold)
{
    const int lane = tid & 63, w = tid >> 6;
    const int nh = w & 1, kh = w >> 1;
    const int m = lane & 15, quad = lane >> 4;
    const int jcol = jb + m;

    stage_h32p(P.hf_bf, sperm, hstage, tid);
    __syncthreads();

    f32x4 accm{}, accl{};
    const int arow = (nh * 16 + m) * HRS + quad * 8;
    const unsigned short* bmp = P.mlW_b + (size_t)jcol * LL + quad * 8;
    const unsigned short* blp = P.mlW_b + (size_t)(LL + jcol) * LL + quad * 8;
    #pragma unroll 4
    for (int c = kh * 16; c < kh * 16 + 16; ++c) {
        const int k0 = c * 32;
        bf16x8 av = *(const bf16x8*)&hstage[arow + k0];
        bf16x8 bm = *(const bf16x8*)(bmp + k0);
        bf16x8 bl = *(const bf16x8*)(blp + k0);
        accm = __builtin_amdgcn_mfma_f32_16x16x32_bf16(av, bm, accm, 0, 0, 0);
        accl = __builtin_amdgcn_mfma_f32_16x16x32_bf16(av, bl, accl, 0, 0, 0);
    }
    if (kh == 1) { red[nh][0][lane] = accm; red[nh][1][lane] = accl; }
    __syncthreads();
    if (kh == 0) {
        accm += red[nh][0][lane]; accl += red[nh][1][lane];
        unsigned short* tr = trb + nh * (16 * 24);
        #pragma unroll
        for (int i = 0; i < 4; ++i) {
            const int n = sperm[nh * 16 + quad * 4 + i];
            float mu = accm[i] + P.mub[jcol];
            float lv = accl[i] + P.lvb[jcol];
            float e = mu + expf(0.5f * lv) * P.eps[(size_t)n * LL + jcol];
            hold[i] = e;
            tr[(quad * 4 + i) * 24 + m] = f2bf(e);
        }
        if (lane < 32) {
            const int nl = lane >> 1, jh = lane & 1;
            bf16x8 vv = *(const bf16x8*)&tr[nl * 24 + jh * 8];
            stg16(P.hdecAb + (size_t)sperm[nh * 16 + nl] * LL + jb + jh * 8, vv);
        }
    }
}

// ---------------------------------------------------------------- MFMA decoder head
// Inlined into matmul blocks lbid<2 (db = lbid): 16 samples, ranks db*16..+15.
// Reads h_{i-1} DIRECTLY from hstage (already staged this iteration).
__device__ void head_tile(const PParams& P, const int* __restrict__ sperm, const int tid,
                          const int db, int ti, unsigned short* hstage, char* shu)
{
    auto& ylds  = *(unsigned short (*)[16][136])(shu);
    auto& y2lds = *(unsigned short (*)[16][72])(shu + 4352);
    float* lred = (float*)(shu + 4352 + 2304);
    const int lane = tid & 63, w = tid >> 6;
    const int m16 = lane & 15, quad = lane >> 4;

    // ---- y1: K=1024, 8 j-tiles, wave w -> {2w, 2w+1}; A rows = hstage[db*16+m16]
    #pragma unroll
    for (int jt = 0; jt < 2; ++jt) {
        const int c0 = (w * 2 + jt) * 16;
        f32x4 acc{};
        const int abase = (db * 16 + m16) * HRS + quad * 8;
        const unsigned short* bp = P.d1Wb + (size_t)(c0 + m16) * LL + quad * 8;
        #pragma unroll 4
        for (int c = 0; c < 32; ++c) {
            bf16x8 av = *(const bf16x8*)&hstage[abase + c * 32];
            bf16x8 bv = *(const bf16x8*)(bp + c * 32);
            acc = __builtin_amdgcn_mfma_f32_16x16x32_bf16(av, bv, acc, 0, 0, 0);
        }
        const float b = P.d1b[c0 + m16];
        #pragma unroll
        for (int i = 0; i < 4; ++i)
            ylds[quad * 4 + i][c0 + m16] = f2bf(fmaxf(acc[i] + b, 0.0f));
    }
    __syncthreads();

    // ---- y2: K=128, wave w -> tile w
    {
        const int c0 = w * 16;
        f32x4 acc{};
        #pragma unroll
        for (int c = 0; c < 4; ++c) {
            bf16x8 av = *(const bf16x8*)&ylds[m16][c * 32 + quad * 8];
            bf16x8 bv = *(const bf16x8*)(P.d2Wb + (size_t)(c0 + m16) * 128 + c * 32 + quad * 8);
            acc = __builtin_amdgcn_mfma_f32_16x16x32_bf16(av, bv, acc, 0, 0, 0);
        }
        const float b = P.d2b[c0 + m16];
        #pragma unroll
        for (int i = 0; i < 4; ++i)
            y2lds[quad * 4 + i][c0 + m16] = f2bf(fmaxf(acc[i] + b, 0.0f));
    }
    __syncthreads();

    // ---- y3: K=64, wave w -> {2w, 2w+1}; fused masked L1
    float lsum = 0.0f;
    #pragma unroll
    for (int jt = 0; jt < 2; ++jt) {
        const int c0 = (w * 2 + jt) * 16;
        f32x4 acc{};
        #pragma unroll
        for (int c = 0; c < 2; ++c) {
            bf16x8 av = *(const bf16x8*)&y2lds[m16][c * 32 + quad * 8];
            bf16x8 bv = *(const bf16x8*)(P.d3Wb + (size_t)(c0 + m16) * 64 + c * 32 + quad * 8);
            acc = __builtin_amdgcn_mfma_f32_16x16x32_bf16(av, bv, acc, 0, 0, 0);
        }
        const int col = c0 + m16;
        const float b = P.d3b[col];
        #pragma unroll
        for (int i = 0; i < 4; ++i) {
            const int n = sperm[db * 16 + quad * 4 + i];
            if (ti < P.limitv[n]) {
                int trw = ti + P.startv[n]; if (trw >= TT) trw -= TT;
                float v = P.s_next[(size_t)n * TT * SS + (size_t)trw * SS + col];
                lsum += fabsf(v - (acc[i] + b));
            }
        }
    }
    for (int off = 32; off >= 1; off >>= 1) lsum += __shfl_down(lsum, off);
    if (lane == 0) lred[w] = lsum;
    __syncthreads();
    if (tid == 0) atomicAdd(P.loss, lred[0] + lred[1] + lred[2] + lred[3]);
}

// ---------------------------------------------------------------- the persistent kernel
__global__ __launch_bounds__(256, 2)
void persist(PParams P)
{
    __shared__ __align__(16) unsigned short hstage[32 * HRS];   // 66176 B
    __shared__ __align__(16) char shu[9728];                    // red/head [0..8192) + tr [8192..9728)
    __shared__ int sperm[32];                                   // group's permuted sample ids
    __shared__ int mint, sME, sML, sbrk;
    f32x4 (&red)[2][4][64] = *(f32x4 (*)[2][4][64])(shu);
    unsigned short* trb = (unsigned short*)(shu + 8192);
    const int bid = blockIdx.x, tid = threadIdx.x;
    const int g = bid & 3, lbid = bid >> 2;    // group g; lbid 0..63 all matmul
    const int jb = lbid * 16;
    int* slots = P.bar + 4608 + g * 256;       // group slot array (1 KB apart)
    int* brk = P.bar + 132;

    // ================= phase 0: cast (plain stores), split detection, h0, adec
    {
        const long N0 = 3072L * 160, N1 = N0 + 3072L * 1024, N2 = N1 + 3072L * 32,
                   N3 = N2 + 3072L * 1024, N4 = N3 + 1048576L, N5 = N4 + 1048576L,
                   N6 = N5 + 128L * 100 * 160, N7 = N6 + 131072L, N8 = N7 + 8192L,
                   N9 = N8 + 8192L;
        for (long i = (long)bid * 256 + tid; i < N9; i += (long)NBLK * 256) {
            if (i < N0)      P.eWih_b[i]      = f2bf(P.eWih[i]);
            else if (i < N1) P.eWhh_b[i - N0] = f2bf(P.eWhh[i - N0]);
            else if (i < N2) P.dWih_b[i - N1] = f2bf(P.dWih[i - N1]);
            else if (i < N3) P.dWhh_b[i - N2] = f2bf(P.dWhh[i - N2]);
            else if (i < N4) P.mlW_b[i - N3]  = f2bf(P.muW[i - N3]);
            else if (i < N5) P.mlW_b[1048576L + (i - N4)] = f2bf(P.lvW[i - N4]);
            else if (i < N6) {
                long j = i - N5;                  // n*16000 + t*160 + k
                int  k = (int)(j % 160);
                long nt = j / 160;
                int  t = (int)(nt % 100), n = (int)(nt / 100);
                float v = (k < SS) ? P.s[(size_t)n * TT * SS + (size_t)t * SS + k]
                                   : P.a[(size_t)n * TT * AA + (size_t)t * AA + (k - SS)];
                P.xenc_b[j] = f2bf(v);
            }
            else if (i < N7) P.d1Wb[i - N6] = f2bf(P.d1W[i - N6]);
            else if (i < N8) P.d2Wb[i - N7] = f2bf(P.d2W[i - N7]);
            else             P.d3Wb[i - N8] = f2bf(P.d3W[i - N8]);
        }
    }
    if (bid < NN_) {
        const int n = bid;
        if (tid == 0) mint = TT - 1;
        __syncthreads();
        int t = tid + 1;
        if (t < TT && tid < 128) {
            const float* row = P.s + (size_t)n * TT * SS + (size_t)t * SS;
            bool allz = true;
            for (int i = 0; i < SS; ++i) { if (row[i] != 0.0f) { allz = false; break; } }
            if (allz) atomicMin(&mint, t);
        }
        __syncthreads();
        const int m = mint, st = m + 1;
        if (tid == 0) { P.endv[n] = m - 1; P.startv[n] = st; P.limitv[n] = TT - 1 - m; }
        for (int idx = tid; idx < LL; idx += 256)
            P.hencAb[(size_t)n * LL + idx] = 0x3F80;   // bf16 1.0
        for (int idx = tid; idx < 50 * AA; idx += 256) {
            int i = idx >> 5, k = idx & 31;
            int tr = i + st; if (tr >= TT) tr -= TT;
            P.adec_b[(size_t)n * (50 * AA) + idx] =
                f2bf(P.a[(size_t)n * TT * AA + (size_t)tr * AA + k]);
        }
    }
    // one-time global heavy barrier: flush phase-0 plain stores, drop stale lines
    __syncthreads();
    if (tid == 0) __threadfence();
    gbar_global(P.bar, bid, tid, 1);
    if (tid == 0) __threadfence();
    __syncthreads();

    // ================= length-sorted permutation (identical in every block)
    {
        int* keys = (int*)shu;
        if (tid < 128) keys[tid] = P.endv[tid];
        if (tid == 0) sbrk = 0;
        __syncthreads();
        if (tid < 128) {
            const int k = keys[tid];
            int r = 0;
            for (int j = 0; j < 128; ++j) {
                const int kj = keys[j];
                r += (kj < k) | ((kj == k) & (j < tid));
            }
            if (r >= g * 32 && r < g * 32 + 32) sperm[r - g * 32] = tid;  // rank -> sample
        }
        __syncthreads();
    }

    // ================= group ME = max(end), ML = max(limit) over its 32 samples
    int ME, ML;
    {
        int lv = 0, ev = 0;
        if (tid < 32) { const int n = sperm[tid]; lv = P.limitv[n]; ev = P.endv[n]; }
        if (tid < 64) {
            for (int off = 16; off >= 1; off >>= 1) {
                lv = max(lv, __shfl_down(lv, off));
                ev = max(ev, __shfl_down(ev, off));
            }
            if (tid == 0) { sML = lv; sME = ev; }
        }
        __syncthreads();
        ML = sML; ME = sME;
        __syncthreads();
    }

    f32x4 hold = { 1.0f, 1.0f, 1.0f, 1.0f };   // enc h0 = ones (fp32 state lives here)
    int ggen = 0;

    // ================= encoder: t = 0..ME_g
    for (int t = 0; t <= ME; ++t) {
        const unsigned short* hib = (t & 1) ? P.hencBb : P.hencAb;
        unsigned short*       hob = (t & 1) ? P.hencAb : P.hencBb;
        gru_tile<160, false>(sperm, jb, tid, hib, hob,
                             P.eWhh_b, P.eWih_b, P.xenc_b, P.ebih, P.ebhh,
                             P.endv, P.hf_bf, t, red, hstage, trb, hold);
        gbar4(slots, brk, lbid, tid, ++ggen, &sbrk);
    }

    // ================= reparametrize (deposits decoder h0 into hold regs)
    emb_tile(P, sperm, jb, tid, red, hstage, trb, hold);
    gbar4(slots, brk, lbid, tid, ++ggen, &sbrk);

    // ================= decoder: i = 0..ML_g
    // hstage after gru_tile (or the explicit stage at i==ML) holds h_{i-1};
    // blocks lbid<2 then run the head for step i-1 on it (16 samples each).
    for (int i = 0; i <= ML; ++i) {
        const unsigned short* hib = (i & 1) ? P.hdecBb : P.hdecAb;
        if (i < ML) {
            unsigned short* hob = (i & 1) ? P.hdecAb : P.hdecBb;
            gru_tile<32, true>(sperm, jb, tid, hib, hob,
                               P.dWhh_b, P.dWih_b, P.adec_b, P.dbih, P.dbhh,
                               nullptr, nullptr, i, red, hstage, trb, hold);
        } else if (lbid < 2) {
            stage_h32p(hib, sperm, hstage, tid);   // final step: no gru staged it
        }
        if (lbid < 2 && i >= 1) {
            __syncthreads();   // red/tr reads done; shu becomes ylds/y2lds
            head_tile(P, sperm, tid, lbid, i - 1, hstage, shu);
        }
        gbar4(slots, brk, lbid, tid, ++ggen, &sbrk);
    }
}

// ---------------------------------------------------------------- launch
extern "C" void kernel_launch(void* const* d_in, const int* in_sizes, int n_in,
                              void* d_out, int out_size, void* d_ws, size_t ws_size,
                              hipStream_t stream) {
    PParams P;
    P.s      = (const float*)d_in[0];
    P.a      = (const float*)d_in[1];
    P.s_next = (const float*)d_in[3];
    P.eps    = (const float*)d_in[4];
    P.eWih   = (const float*)d_in[5];
    P.eWhh   = (const float*)d_in[6];
    P.ebih   = (const float*)d_in[7];
    P.ebhh   = (const float*)d_in[8];
    P.muW    = (const float*)d_in[9];
    P.mub    = (const float*)d_in[10];
    P.lvW    = (const float*)d_in[11];
    P.lvb    = (const float*)d_in[12];
    // st1..st3 (13..18) dead code w.r.t. the loss
    P.dWih   = (const float*)d_in[19];
    P.dWhh   = (const float*)d_in[20];
    P.dbih   = (const float*)d_in[21];
    P.dbhh   = (const float*)d_in[22];
    P.d1W    = (const float*)d_in[23];
    P.d1b    = (const float*)d_in[24];
    P.d2W    = (const float*)d_in[25];
    P.d2b    = (const float*)d_in[26];
    P.d3W    = (const float*)d_in[27];
    P.d3b    = (const float*)d_in[28];
    P.loss   = (float*)d_out;

    char* p = (char*)d_ws;
    P.bar    = (int*)p;                    p += 24576;   // 6144 ints (barriers)
    P.endv   = (int*)p;                    p += 512;
    P.startv = (int*)p;                    p += 512;
    P.limitv = (int*)p;                    p += 512;
    p += 2560;                             // pad
    P.hencAb = (unsigned short*)p;         p += 128 * 1024 * 2;
    P.hencBb = (unsigned short*)p;         p += 128 * 1024 * 2;
    P.hdecAb = (unsigned short*)p;         p += 128 * 1024 * 2;
    P.hdecBb = (unsigned short*)p;         p += 128 * 1024 * 2;
    P.hf_bf  = (unsigned short*)p;         p += 128 * 1024 * 2;
    P.eWih_b = (unsigned short*)p;         p += 3072 * 160 * 2;
    P.eWhh_b = (unsigned short*)p;         p += 3072 * 1024 * 2;
    P.dWih_b = (unsigned short*)p;         p += 3072 * 32 * 2;
    P.dWhh_b = (unsigned short*)p;         p += 3072 * 1024 * 2;
    P.mlW_b  = (unsigned short*)p;         p += 2048 * 1024 * 2;
    P.xenc_b = (unsigned short*)p;         p += 128 * 100 * 160 * 2;
    P.adec_b = (unsigned short*)p;         p += 128 * 50 * 32 * 2;
    P.d1Wb   = (unsigned short*)p;         p += 128 * 1024 * 2;
    P.d2Wb   = (unsigned short*)p;         p += 64 * 128 * 2;
    P.d3Wb   = (unsigned short*)p;         p += 128 * 64 * 2;

    hipLaunchKernelGGL(init_kernel, dim3(1), dim3(256), 0, stream, P.bar, P.loss);
    hipLaunchKernelGGL(persist, dim3(NBLK), dim3(256), 0, stream, P);
}

// Round 8
// 2129.693 us; speedup vs baseline: 1.0509x; 1.0509x over previous
//
#include <hip/hip_runtime.h>
#include <math.h>

#define NN_ 128   // batch
#define TT  100   // time steps
#define SS  128   // state dim
#define AA  32    // action dim
#define LL  1024  // hidden (= Z)
#define NBLK 264  // 4 groups x 66; 64 matmul blocks + 2 head blocks per group
#define HRS  1034 // LDS h-stage row stride (bf16): max 2-way bank aliasing (free)

// Round-8: round-7 retry (compile fix only). r3 base + exponential-backoff
// barrier poll. s_sleep requires a CONSTANT arg -> constant ladder 8/16/32/64.
// Theory: continuous poll storm congests the flag line (queued line service),
// setting the ~17us/step floor across all barrier variants; backoff cuts the
// aggregate poll rate ~20x below the line service rate.
// All cross-block ops remain proven-coherent: __hip_atomic_* AGENT + "sc0 sc1".

typedef __attribute__((ext_vector_type(8))) short bf16x8;   // 8 bf16 in 4 VGPRs
typedef __attribute__((ext_vector_type(4))) float f32x4;
typedef __attribute__((ext_vector_type(4))) int   i32x4;

__device__ __forceinline__ float sigmoidf_(float x) { return 1.0f / (1.0f + expf(-x)); }
__device__ __forceinline__ unsigned short f2bf(float x) {
    union { float f; unsigned u; } v; v.f = x;
    return (unsigned short)((v.u + 0x7fffu + ((v.u >> 16) & 1u)) >> 16);   // RNE
}

// ---- coherent access helpers (system scope: sc0 sc1) -----------------------
__device__ __forceinline__ i32x4 ldg16(const unsigned short* p) {
    i32x4 r; asm volatile("global_load_dwordx4 %0, %1, off sc0 sc1"
                          : "=&v"(r) : "v"((unsigned long long)p));
    return r;   // caller must s_waitcnt vmcnt(0) before use
}
__device__ __forceinline__ void stg16(unsigned short* p, bf16x8 v) {
    union { bf16x8 h; i32x4 i; } u; u.h = v;
    asm volatile("global_store_dwordx4 %0, %1, off sc0 sc1"
                 :: "v"((unsigned long long)p), "v"(u.i) : "memory");
}
__device__ __forceinline__ void st2(unsigned short* p, unsigned short v) {
    asm volatile("global_store_short %0, %1, off sc0 sc1"
                 :: "v"((unsigned long long)p), "v"((unsigned)v) : "memory");
}
__device__ __forceinline__ int aload(const int* p) {
    return __hip_atomic_load(p, __ATOMIC_RELAXED, __HIP_MEMORY_SCOPE_AGENT);
}
__device__ __forceinline__ void astore(int* p, int v) {
    __hip_atomic_store(p, v, __ATOMIC_RELAXED, __HIP_MEMORY_SCOPE_AGENT);
}

struct PParams {
    const float *s, *a, *s_next, *eps;
    const float *eWih, *eWhh, *ebih, *ebhh;
    const float *muW, *mub, *lvW, *lvb;
    const float *dWih, *dWhh, *dbih, *dbhh;
    const float *d1W, *d1b, *d2W, *d2b, *d3W, *d3b;
    int *bar;
    int *endv, *startv, *limitv;
    unsigned short *hencAb, *hencBb, *hdecAb, *hdecBb, *hf_bf;
    unsigned short *eWih_b, *eWhh_b, *dWih_b, *dWhh_b, *mlW_b, *xenc_b, *adec_b;
    unsigned short *d1Wb, *d2Wb, *d3Wb;
    float *loss;
};

// ---------------------------------------------------------------- h-tile stages
// 32 rows (permuted) x 1024 cols bf16 (64 KB): 16 x 16B loads per thread.
__device__ __forceinline__ void stage_h32p(const unsigned short* __restrict__ src,
                                           const int* __restrict__ sperm,
                                           unsigned short* hstage, int tid) {
    i32x4 v[16];
    const int p = tid >> 7, col = (tid & 127) * 8;
    #pragma unroll
    for (int k = 0; k < 16; ++k) {
        const int row = sperm[p + 2 * k];           // physical sample id
        v[k] = ldg16(src + (size_t)row * LL + col);
    }
    asm volatile("s_waitcnt vmcnt(0)" ::: "memory");
    #pragma unroll
    for (int k = 0; k < 16; ++k)
        *(i32x4*)&hstage[(p + 2 * k) * HRS + col] = v[k];
}
// 16 rows (head blocks), sperm16 = rank base of this head block
__device__ __forceinline__ void stage_h16p(const unsigned short* __restrict__ src,
                                           const int* __restrict__ sperm16,
                                           unsigned short* hstage, int tid) {
    i32x4 v[8];
    const int p = tid >> 7, col = (tid & 127) * 8;
    #pragma unroll
    for (int k = 0; k < 8; ++k) {
        const int row = sperm16[p + 2 * k];
        v[k] = ldg16(src + (size_t)row * LL + col);
    }
    asm volatile("s_waitcnt vmcnt(0)" ::: "memory");
    #pragma unroll
    for (int k = 0; k < 8; ++k)
        *(i32x4*)&hstage[(p + 2 * k) * HRS + col] = v[k];
}

// ---------------------------------------------------------------- barriers
// Global (phase 0 only): bar[g8*16] 8 counters; [128] master; [132] broken;
// [144+b*16] flags. 264/8 = 33 per class.
__device__ void gbar_global(int* bar, int bid, int tid, int gen) {
    __syncthreads();
    if (tid == 0) {
        if (aload(bar + 132) == 0) {
            const int g8 = bid & 7;
            int pos = __hip_atomic_fetch_add(bar + g8 * 16, 1, __ATOMIC_RELAXED, __HIP_MEMORY_SCOPE_AGENT);
            if (pos + 1 == (NBLK / 8) * gen) {
                int mp = __hip_atomic_fetch_add(bar + 128, 1, __ATOMIC_RELAXED, __HIP_MEMORY_SCOPE_AGENT);
                if (mp + 1 == 8 * gen) {
                    for (int b = 0; b < NBLK; ++b)
                        astore(bar + 144 + b * 16, gen);
                }
            }
            int it = 0;
            while (aload(bar + 144 + bid * 16) < gen) {
                __builtin_amdgcn_s_sleep(1);
                if (++it > 4000000) { astore(bar + 132, 1); break; }
            }
        }
    }
    __syncthreads();
}

// Group-local per-step barrier (r3 mechanics): gb[0,16,32,48] 4 sub-counters
// (17/17/16/16 of the 66 blocks); gb[64] master; gb[80] flag. Monotone gens.
// ROUND-8 CHANGE: exponential-backoff poll via CONSTANT s_sleep ladder
// (8 -> 16 -> 32 -> 64, i.e. ~0.21 -> 1.7us) to kill the poll storm.
__device__ void gbar_group(int* gb, int* brk, int lbid, int tid, int gen, int* sbrk) {
    asm volatile("s_waitcnt vmcnt(0)" ::: "memory");   // drain this wave's h stores
    __syncthreads();
    if (tid == 0) {
        const int s = lbid & 3;
        const int tgt = (s < 2) ? 17 : 16;   // 66 = 17+17+16+16
        int pos = __hip_atomic_fetch_add(gb + s * 16, 1, __ATOMIC_RELAXED, __HIP_MEMORY_SCOPE_AGENT);
        if (pos + 1 == tgt * gen) {
            int mp = __hip_atomic_fetch_add(gb + 64, 1, __ATOMIC_RELAXED, __HIP_MEMORY_SCOPE_AGENT);
            if (mp + 1 == 4 * gen)
                astore(gb + 80, gen);
        }
        if (*sbrk == 0) {
            if (aload(gb + 80) < gen) {        // immediate check (released-already case)
                int it = 0;
                for (;;) {
                    if      (it == 0) __builtin_amdgcn_s_sleep(8);   //  512 clk ~0.21us
                    else if (it == 1) __builtin_amdgcn_s_sleep(16);  // 1024 clk ~0.43us
                    else if (it == 2) __builtin_amdgcn_s_sleep(32);  // 2048 clk ~0.85us
                    else              __builtin_amdgcn_s_sleep(64);  // 4096 clk ~1.7us
                    if (aload(gb + 80) >= gen) break;
                    if (((++it) & 31) == 0) {
                        if (aload(brk)) { *sbrk = 1; break; }
                        if (it > 100000) { astore(brk, 1); *sbrk = 1; break; }  // ~170ms
                    }
                }
            }
        }
    }
    __syncthreads();
}

// ---------------------------------------------------------------- init (separate launch)
__global__ void init_kernel(int* bar, float* loss) {
    for (int i = threadIdx.x; i < 5632; i += 256) bar[i] = 0;
    if (threadIdx.x == 0) loss[0] = 0.0f;
}

// ---------------------------------------------------------------- GRU step matmul tile
// Per group: 64 blocks x 16 j-cols (3 gates), 32 samples (permuted via sperm).
// Waves: nh=w&1 sample-half, kh=w>>1 K-half. fp32 h state lives in `hold` regs
// of kh==0 waves; h stores coalesced 16B system-scope via LDS transpose.
template<int XK, bool IS_DEC>
__device__ void gru_tile(const int* __restrict__ sperm, const int jb, const int tid,
    const unsigned short* __restrict__ h_bf, unsigned short* __restrict__ ho_bf,
    const unsigned short* __restrict__ Whh_b, const unsigned short* __restrict__ Wih_b,
    const unsigned short* __restrict__ x_bf,
    const float* __restrict__ bih, const float* __restrict__ bhh,
    const int* __restrict__ endv, unsigned short* __restrict__ hf_bf,
    int t, f32x4 (&red)[2][4][64], unsigned short* hstage, f32x4& hold)
{
    const int lane = tid & 63, w = tid >> 6;
    const int nh = w & 1, kh = w >> 1;
    const int m = lane & 15, quad = lane >> 4;
    const int jcol = jb + m;

    stage_h32p(h_bf, sperm, hstage, tid);
    __syncthreads();

    f32x4 accr{}, accz{}, acchn{}, accxn{};

    {   // hidden: K = 1024, 32 chunks, split 16/16 across kh; A from LDS
        const int arow = (nh * 16 + m) * HRS + quad * 8;
        const unsigned short* brp = Whh_b + (size_t)(0 * LL + jcol) * LL + quad * 8;
        const unsigned short* bzp = Whh_b + (size_t)(1 * LL + jcol) * LL + quad * 8;
        const unsigned short* bnp = Whh_b + (size_t)(2 * LL + jcol) * LL + quad * 8;
        #pragma unroll 4
        for (int c = kh * 16; c < kh * 16 + 16; ++c) {
            const int k0 = c * 32;
            bf16x8 av = *(const bf16x8*)&hstage[arow + k0];
            bf16x8 br = *(const bf16x8*)(brp + k0);
            bf16x8 bz = *(const bf16x8*)(bzp + k0);
            bf16x8 bn = *(const bf16x8*)(bnp + k0);
            accr  = __builtin_amdgcn_mfma_f32_16x16x32_bf16(av, br, accr, 0, 0, 0);
            accz  = __builtin_amdgcn_mfma_f32_16x16x32_bf16(av, bz, accz, 0, 0, 0);
            acchn = __builtin_amdgcn_mfma_f32_16x16x32_bf16(av, bn, acchn, 0, 0, 0);
        }
    }
    {   // input: K = XK (enc 160, dec 32); read-only -> plain L1/L2-cached loads
        const int XC = XK / 32, XC0 = (XC + 1) / 2;
        const size_t xstride = IS_DEC ? (size_t)(50 * AA) : (size_t)(TT * (SS + AA));
        const int nphys = sperm[nh * 16 + m];
        const unsigned short* xp  = x_bf + (size_t)nphys * xstride + (size_t)t * XK + quad * 8;
        const unsigned short* brp = Wih_b + (size_t)(0 * LL + jcol) * XK + quad * 8;
        const unsigned short* bzp = Wih_b + (size_t)(1 * LL + jcol) * XK + quad * 8;
        const unsigned short* bnp = Wih_b + (size_t)(2 * LL + jcol) * XK + quad * 8;
        #pragma unroll
        for (int c = (kh ? XC0 : 0); c < (kh ? XC : XC0); ++c) {
            const int k0 = c * 32;
            bf16x8 av = *(const bf16x8*)(xp + k0);
            bf16x8 br = *(const bf16x8*)(brp + k0);
            bf16x8 bz = *(const bf16x8*)(bzp + k0);
            bf16x8 bn = *(const bf16x8*)(bnp + k0);
            accr  = __builtin_amdgcn_mfma_f32_16x16x32_bf16(av, br, accr, 0, 0, 0);
            accz  = __builtin_amdgcn_mfma_f32_16x16x32_bf16(av, bz, accz, 0, 0, 0);
            accxn = __builtin_amdgcn_mfma_f32_16x16x32_bf16(av, bn, accxn, 0, 0, 0);
        }
    }
    if (kh == 1) {
        red[nh][0][lane] = accr;  red[nh][1][lane] = accz;
        red[nh][2][lane] = acchn; red[nh][3][lane] = accxn;
    }
    __syncthreads();
    if (kh == 0) {
        accr  += red[nh][0][lane];  accz  += red[nh][1][lane];
        acchn += red[nh][2][lane];  accxn += red[nh][3][lane];
        const float br_  = bih[jcol] + bhh[jcol];
        const float bz_  = bih[LL + jcol] + bhh[LL + jcol];
        const float bxn_ = bih[2 * LL + jcol];
        const float bhn_ = bhh[2 * LL + jcol];
        unsigned short* tr = hstage + nh * (16 * 24);    // wave-private transpose scratch
        #pragma unroll
        for (int i = 0; i < 4; ++i) {
            const int n = sperm[nh * 16 + quad * 4 + i]; // C layout: row=quad*4+i, col=m
            float r = sigmoidf_(accr[i] + br_);
            float z = sigmoidf_(accz[i] + bz_);
            float g = tanhf(accxn[i] + bxn_ + r * (acchn[i] + bhn_));
            float hn = (1.0f - z) * g + z * hold[i];
            hold[i] = hn;
            unsigned short hb = f2bf(hn);
            tr[(quad * 4 + i) * 24 + m] = hb;            // LDS transpose (wave-lockstep)
            if (!IS_DEC) { if (endv[n] == t) st2(hf_bf + (size_t)n * LL + jcol, hb); }
        }
        // coalesced 16B n-major stores: lanes 0..31 each store 8 bf16
        if (lane < 32) {
            const int nl = lane >> 1, jh = lane & 1;
            bf16x8 vv = *(const bf16x8*)&tr[nl * 24 + jh * 8];
            stg16(ho_bf + (size_t)sperm[nh * 16 + nl] * LL + jb + jh * 8, vv);
        }
    }
}

// ---------------------------------------------------------------- reparametrize tile
__device__ void emb_tile(const PParams& P, const int* __restrict__ sperm, const int jb,
                         const int tid, f32x4 (&red)[2][4][64], unsigned short* hstage,
                         f32x4& hold)
{
    const int lane = tid & 63, w = tid >> 6;
    const int nh = w & 1, kh = w >> 1;
    const int m = lane & 15, quad = lane >> 4;
    const int jcol = jb + m;

    stage_h32p(P.hf_bf, sperm, hstage, tid);
    __syncthreads();

    f32x4 accm{}, accl{};
    const int arow = (nh * 16 + m) * HRS + quad * 8;
    const unsigned short* bmp = P.mlW_b + (size_t)jcol * LL + quad * 8;
    const unsigned short* blp = P.mlW_b + (size_t)(LL + jcol) * LL + quad * 8;
    #pragma unroll 4
    for (int c = kh * 16; c < kh * 16 + 16; ++c) {
        const int k0 = c * 32;
        bf16x8 av = *(const bf16x8*)&hstage[arow + k0];
        bf16x8 bm = *(const bf16x8*)(bmp + k0);
        bf16x8 bl = *(const bf16x8*)(blp + k0);
        accm = __builtin_amdgcn_mfma_f32_16x16x32_bf16(av, bm, accm, 0, 0, 0);
        accl = __builtin_amdgcn_mfma_f32_16x16x32_bf16(av, bl, accl, 0, 0, 0);
    }
    if (kh == 1) { red[nh][0][lane] = accm; red[nh][1][lane] = accl; }
    __syncthreads();
    if (kh == 0) {
        accm += red[nh][0][lane]; accl += red[nh][1][lane];
        unsigned short* tr = hstage + nh * (16 * 24);
        #pragma unroll
        for (int i = 0; i < 4; ++i) {
            const int n = sperm[nh * 16 + quad * 4 + i];
            float mu = accm[i] + P.mub[jcol];
            float lv = accl[i] + P.lvb[jcol];
            float e = mu + expf(0.5f * lv) * P.eps[(size_t)n * LL + jcol];
            hold[i] = e;
            tr[(quad * 4 + i) * 24 + m] = f2bf(e);
        }
        if (lane < 32) {
            const int nl = lane >> 1, jh = lane & 1;
            bf16x8 vv = *(const bf16x8*)&tr[nl * 24 + jh * 8];
            stg16(P.hdecAb + (size_t)sperm[nh * 16 + nl] * LL + jb + jh * 8, vv);
        }
    }
}

// ---------------------------------------------------------------- MFMA decoder head
// Two blocks per group, 16 (permuted) samples each. sperm16 = sperm + 16*(lbid-64).
__device__ void head_tile(const PParams& P, const int* __restrict__ sperm16, const int tid,
                          const unsigned short* __restrict__ h_bf, int ti,
                          unsigned short* hstage, char* shu)
{
    auto& ylds  = *(unsigned short (*)[16][136])(shu);
    auto& y2lds = *(unsigned short (*)[16][72])(shu + 4352);
    float* lred = (float*)(shu + 4352 + 2304);
    const int lane = tid & 63, w = tid >> 6;
    const int m16 = lane & 15, quad = lane >> 4;

    stage_h16p(h_bf, sperm16, hstage, tid);
    __syncthreads();

    // ---- y1: K=1024, 8 j-tiles, wave w -> {2w, 2w+1}
    #pragma unroll
    for (int jt = 0; jt < 2; ++jt) {
        const int c0 = (w * 2 + jt) * 16;
        f32x4 acc{};
        const int abase = m16 * HRS + quad * 8;
        const unsigned short* bp = P.d1Wb + (size_t)(c0 + m16) * LL + quad * 8;
        #pragma unroll 4
        for (int c = 0; c < 32; ++c) {
            bf16x8 av = *(const bf16x8*)&hstage[abase + c * 32];
            bf16x8 bv = *(const bf16x8*)(bp + c * 32);
            acc = __builtin_amdgcn_mfma_f32_16x16x32_bf16(av, bv, acc, 0, 0, 0);
        }
        const float b = P.d1b[c0 + m16];
        #pragma unroll
        for (int i = 0; i < 4; ++i)
            ylds[quad * 4 + i][c0 + m16] = f2bf(fmaxf(acc[i] + b, 0.0f));
    }
    __syncthreads();

    // ---- y2: K=128, wave w -> tile w
    {
        const int c0 = w * 16;
        f32x4 acc{};
        #pragma unroll
        for (int c = 0; c < 4; ++c) {
            bf16x8 av = *(const bf16x8*)&ylds[m16][c * 32 + quad * 8];
            bf16x8 bv = *(const bf16x8*)(P.d2Wb + (size_t)(c0 + m16) * 128 + c * 32 + quad * 8);
            acc = __builtin_amdgcn_mfma_f32_16x16x32_bf16(av, bv, acc, 0, 0, 0);
        }
        const float b = P.d2b[c0 + m16];
        #pragma unroll
        for (int i = 0; i < 4; ++i)
            y2lds[quad * 4 + i][c0 + m16] = f2bf(fmaxf(acc[i] + b, 0.0f));
    }
    __syncthreads();

    // ---- y3: K=64, wave w -> {2w, 2w+1}; fused masked L1
    float lsum = 0.0f;
    #pragma unroll
    for (int jt = 0; jt < 2; ++jt) {
        const int c0 = (w * 2 + jt) * 16;
        f32x4 acc{};
        #pragma unroll
        for (int c = 0; c < 2; ++c) {
            bf16x8 av = *(const bf16x8*)&y2lds[m16][c * 32 + quad * 8];
            bf16x8 bv = *(const bf16x8*)(P.d3Wb + (size_t)(c0 + m16) * 64 + c * 32 + quad * 8);
            acc = __builtin_amdgcn_mfma_f32_16x16x32_bf16(av, bv, acc, 0, 0, 0);
        }
        const int col = c0 + m16;
        const float b = P.d3b[col];
        #pragma unroll
        for (int i = 0; i < 4; ++i) {
            const int n = sperm16[quad * 4 + i];
            if (ti < P.limitv[n]) {
                int trw = ti + P.startv[n]; if (trw >= TT) trw -= TT;
                float v = P.s_next[(size_t)n * TT * SS + (size_t)trw * SS + col];
                lsum += fabsf(v - (acc[i] + b));
            }
        }
    }
    for (int off = 32; off >= 1; off >>= 1) lsum += __shfl_down(lsum, off);
    if (lane == 0) lred[w] = lsum;
    __syncthreads();
    if (tid == 0) atomicAdd(P.loss, lred[0] + lred[1] + lred[2] + lred[3]);
}

// ---------------------------------------------------------------- the persistent kernel
__global__ __launch_bounds__(256, 2)
void persist(PParams P)
{
    __shared__ __align__(16) unsigned short hstage[32 * HRS];   // 66176 B
    __shared__ __align__(16) char shu[8192];                    // red OR head ylds/y2lds/lred OR sort keys
    __shared__ int sperm[32];                                   // group's permuted sample ids
    __shared__ int mint, sME, sML, sbrk;
    f32x4 (&red)[2][4][64] = *(f32x4 (*)[2][4][64])(shu);
    const int bid = blockIdx.x, tid = threadIdx.x;
    const int g = bid & 3, lbid = bid >> 2;    // group g; lbid 0..63 matmul, 64..65 head
    const int jb = lbid * 16;                  // matmul blocks only (lbid < 64)
    int* gb = P.bar + 4608 + g * 128;          // group barrier state (512 B apart)
    int* brk = P.bar + 132;

    // ================= phase 0: cast (plain stores), split detection, h0, adec
    {
        const long N0 = 3072L * 160, N1 = N0 + 3072L * 1024, N2 = N1 + 3072L * 32,
                   N3 = N2 + 3072L * 1024, N4 = N3 + 1048576L, N5 = N4 + 1048576L,
                   N6 = N5 + 128L * 100 * 160, N7 = N6 + 131072L, N8 = N7 + 8192L,
                   N9 = N8 + 8192L;
        for (long i = (long)bid * 256 + tid; i < N9; i += (long)NBLK * 256) {
            if (i < N0)      P.eWih_b[i]      = f2bf(P.eWih[i]);
            else if (i < N1) P.eWhh_b[i - N0] = f2bf(P.eWhh[i - N0]);
            else if (i < N2) P.dWih_b[i - N1] = f2bf(P.dWih[i - N1]);
            else if (i < N3) P.dWhh_b[i - N2] = f2bf(P.dWhh[i - N2]);
            else if (i < N4) P.mlW_b[i - N3]  = f2bf(P.muW[i - N3]);
            else if (i < N5) P.mlW_b[1048576L + (i - N4)] = f2bf(P.lvW[i - N4]);
            else if (i < N6) {
                long j = i - N5;                  // n*16000 + t*160 + k
                int  k = (int)(j % 160);
                long nt = j / 160;
                int  t = (int)(nt % 100), n = (int)(nt / 100);
                float v = (k < SS) ? P.s[(size_t)n * TT * SS + (size_t)t * SS + k]
                                   : P.a[(size_t)n * TT * AA + (size_t)t * AA + (k - SS)];
                P.xenc_b[j] = f2bf(v);
            }
            else if (i < N7) P.d1Wb[i - N6] = f2bf(P.d1W[i - N6]);
            else if (i < N8) P.d2Wb[i - N7] = f2bf(P.d2W[i - N7]);
            else             P.d3Wb[i - N8] = f2bf(P.d3W[i - N8]);
        }
    }
    if (bid < NN_) {
        const int n = bid;
        if (tid == 0) mint = TT - 1;
        __syncthreads();
        int t = tid + 1;
        if (t < TT && tid < 128) {
            const float* row = P.s + (size_t)n * TT * SS + (size_t)t * SS;
            bool allz = true;
            for (int i = 0; i < SS; ++i) { if (row[i] != 0.0f) { allz = false; break; } }
            if (allz) atomicMin(&mint, t);
        }
        __syncthreads();
        const int m = mint, st = m + 1;
        if (tid == 0) { P.endv[n] = m - 1; P.startv[n] = st; P.limitv[n] = TT - 1 - m; }
        for (int idx = tid; idx < LL; idx += 256)
            P.hencAb[(size_t)n * LL + idx] = 0x3F80;   // bf16 1.0
        for (int idx = tid; idx < 50 * AA; idx += 256) {
            int i = idx >> 5, k = idx & 31;
            int tr = i + st; if (tr >= TT) tr -= TT;
            P.adec_b[(size_t)n * (50 * AA) + idx] =
                f2bf(P.a[(size_t)n * TT * AA + (size_t)tr * AA + k]);
        }
    }
    // one-time global heavy barrier: flush phase-0 plain stores, drop stale lines
    __syncthreads();
    if (tid == 0) __threadfence();
    gbar_global(P.bar, bid, tid, 1);
    if (tid == 0) __threadfence();
    __syncthreads();

    // ================= length-sorted permutation (identical in every block)
    {
        int* keys = (int*)shu;
        if (tid < 128) keys[tid] = P.endv[tid];
        if (tid == 0) sbrk = 0;
        __syncthreads();
        if (tid < 128) {
            const int k = keys[tid];
            int r = 0;
            for (int j = 0; j < 128; ++j) {
                const int kj = keys[j];
                r += (kj < k) | ((kj == k) & (j < tid));
            }
            if (r >= g * 32 && r < g * 32 + 32) sperm[r - g * 32] = tid;  // rank -> sample
        }
        __syncthreads();
    }

    // ================= group ME = max(end), ML = max(limit) over its 32 samples
    int ME, ML;
    {
        int lv = 0, ev = 0;
        if (tid < 32) { const int n = sperm[tid]; lv = P.limitv[n]; ev = P.endv[n]; }
        if (tid < 64) {
            for (int off = 16; off >= 1; off >>= 1) {
                lv = max(lv, __shfl_down(lv, off));
                ev = max(ev, __shfl_down(ev, off));
            }
            if (tid == 0) { sML = lv; sME = ev; }
        }
        __syncthreads();
        ML = sML; ME = sME;
        __syncthreads();
    }

    f32x4 hold = { 1.0f, 1.0f, 1.0f, 1.0f };   // enc h0 = ones (fp32 state lives here)
    int ggen = 0;

    // ================= encoder: t = 0..ME_g
    for (int t = 0; t <= ME; ++t) {
        if (lbid < 64) {
            const unsigned short* hib = (t & 1) ? P.hencBb : P.hencAb;
            unsigned short*       hob = (t & 1) ? P.hencAb : P.hencBb;
            gru_tile<160, false>(sperm, jb, tid, hib, hob,
                                 P.eWhh_b, P.eWih_b, P.xenc_b, P.ebih, P.ebhh,
                                 P.endv, P.hf_bf, t, red, hstage, hold);
        }
        gbar_group(gb, brk, lbid, tid, ++ggen, &sbrk);
    }

    // ================= reparametrize (deposits decoder h0 into hold regs)
    if (lbid < 64) emb_tile(P, sperm, jb, tid, red, hstage, hold);
    gbar_group(gb, brk, lbid, tid, ++ggen, &sbrk);

    // ================= decoder: i = 0..ML_g; matmul (i<ML) overlaps head for step i-1
    for (int i = 0; i <= ML; ++i) {
        const unsigned short* hib = (i & 1) ? P.hdecBb : P.hdecAb;
        if (lbid < 64) {
            if (i < ML) {
                unsigned short* hob = (i & 1) ? P.hdecAb : P.hdecBb;
                gru_tile<32, true>(sperm, jb, tid, hib, hob,
                                   P.dWhh_b, P.dWih_b, P.adec_b, P.dbih, P.dbhh,
                                   nullptr, nullptr, i, red, hstage, hold);
            }
        } else if (i >= 1) {
            head_tile(P, sperm + (lbid - 64) * 16, tid, hib, i - 1, hstage, shu);
        }
        gbar_group(gb, brk, lbid, tid, ++ggen, &sbrk);
    }
}

// ---------------------------------------------------------------- launch
extern "C" void kernel_launch(void* const* d_in, const int* in_sizes, int n_in,
                              void* d_out, int out_size, void* d_ws, size_t ws_size,
                              hipStream_t stream) {
    PParams P;
    P.s      = (const float*)d_in[0];
    P.a      = (const float*)d_in[1];
    P.s_next = (const float*)d_in[3];
    P.eps    = (const float*)d_in[4];
    P.eWih   = (const float*)d_in[5];
    P.eWhh   = (const float*)d_in[6];
    P.ebih   = (const float*)d_in[7];
    P.ebhh   = (const float*)d_in[8];
    P.muW    = (const float*)d_in[9];
    P.mub    = (const float*)d_in[10];
    P.lvW    = (const float*)d_in[11];
    P.lvb    = (const float*)d_in[12];
    // st1..st3 (13..18) dead code w.r.t. the loss
    P.dWih   = (const float*)d_in[19];
    P.dWhh   = (const float*)d_in[20];
    P.dbih   = (const float*)d_in[21];
    P.dbhh   = (const float*)d_in[22];
    P.d1W    = (const float*)d_in[23];
    P.d1b    = (const float*)d_in[24];
    P.d2W    = (const float*)d_in[25];
    P.d2b    = (const float*)d_in[26];
    P.d3W    = (const float*)d_in[27];
    P.d3b    = (const float*)d_in[28];
    P.loss   = (float*)d_out;

    char* p = (char*)d_ws;
    P.bar    = (int*)p;                    p += 24576;   // 6144 ints (barriers)
    P.endv   = (int*)p;                    p += 512;
    P.startv = (int*)p;                    p += 512;
    P.limitv = (int*)p;                    p += 512;
    p += 2560;                             // pad
    P.hencAb = (unsigned short*)p;         p += 128 * 1024 * 2;
    P.hencBb = (unsigned short*)p;         p += 128 * 1024 * 2;
    P.hdecAb = (unsigned short*)p;         p += 128 * 1024 * 2;
    P.hdecBb = (unsigned short*)p;         p += 128 * 1024 * 2;
    P.hf_bf  = (unsigned short*)p;         p += 128 * 1024 * 2;
    P.eWih_b = (unsigned short*)p;         p += 3072 * 160 * 2;
    P.eWhh_b = (unsigned short*)p;         p += 3072 * 1024 * 2;
    P.dWih_b = (unsigned short*)p;         p += 3072 * 32 * 2;
    P.dWhh_b = (unsigned short*)p;         p += 3072 * 1024 * 2;
    P.mlW_b  = (unsigned short*)p;         p += 2048 * 1024 * 2;
    P.xenc_b = (unsigned short*)p;         p += 128 * 100 * 160 * 2;
    P.adec_b = (unsigned short*)p;         p += 128 * 50 * 32 * 2;
    P.d1Wb   = (unsigned short*)p;         p += 128 * 1024 * 2;
    P.d2Wb   = (unsigned short*)p;         p += 64 * 128 * 2;
    P.d3Wb   = (unsigned short*)p;         p += 128 * 64 * 2;

    hipLaunchKernelGGL(init_kernel, dim3(1), dim3(256), 0, stream, P.bar, P.loss);
    hipLaunchKernelGGL(persist, dim3(NBLK), dim3(256), 0, stream, P);
}

// Round 9
// 1759.512 us; speedup vs baseline: 1.2719x; 1.2104x over previous
//
#include <hip/hip_runtime.h>
#include <math.h>

#define NN_ 128   // batch
#define TT  100   // time steps
#define SS  128   // state dim
#define AA  32    // action dim
#define LL  1024  // hidden (= Z)
#define NBLK 256  // 4 groups x 64 blocks -- exactly 1 block/CU, ZERO compute stragglers
#define HRS  1034 // LDS h-stage row stride (bf16): max 2-way bank aliasing (free)

// Round-9: balanced-256. All prior configs had a ~2x per-step straggler the
// barrier waits on (264>256 -> doubled CUs, or inline full head on 2 blocks).
// Now: 256 blocks, r3's proven barrier, and the decoder head PIPELINED (depth
// 3) and spread thin: y1 on blocks 48-63 (1 tile each, from own hstage),
// y2 on 32-39, y3+loss on 0-15 (loss in regs, ONE atomicAdd at end).
// All cross-block ops: __hip_atomic_* AGENT + asm "sc0 sc1" (proven classes).

typedef __attribute__((ext_vector_type(8))) short bf16x8;   // 8 bf16 in 4 VGPRs
typedef __attribute__((ext_vector_type(4))) float f32x4;
typedef __attribute__((ext_vector_type(4))) int   i32x4;

__device__ __forceinline__ float sigmoidf_(float x) { return 1.0f / (1.0f + expf(-x)); }
__device__ __forceinline__ unsigned short f2bf(float x) {
    union { float f; unsigned u; } v; v.f = x;
    return (unsigned short)((v.u + 0x7fffu + ((v.u >> 16) & 1u)) >> 16);   // RNE
}

// ---- coherent access helpers (system scope: sc0 sc1) -----------------------
__device__ __forceinline__ i32x4 ldg16(const unsigned short* p) {
    i32x4 r; asm volatile("global_load_dwordx4 %0, %1, off sc0 sc1"
                          : "=&v"(r) : "v"((unsigned long long)p));
    return r;   // caller must s_waitcnt vmcnt(0) before use
}
__device__ __forceinline__ void stg16(unsigned short* p, bf16x8 v) {
    union { bf16x8 h; i32x4 i; } u; u.h = v;
    asm volatile("global_store_dwordx4 %0, %1, off sc0 sc1"
                 :: "v"((unsigned long long)p), "v"(u.i) : "memory");
}
__device__ __forceinline__ void st2(unsigned short* p, unsigned short v) {
    asm volatile("global_store_short %0, %1, off sc0 sc1"
                 :: "v"((unsigned long long)p), "v"((unsigned)v) : "memory");
}
__device__ __forceinline__ int aload(const int* p) {
    return __hip_atomic_load(p, __ATOMIC_RELAXED, __HIP_MEMORY_SCOPE_AGENT);
}
__device__ __forceinline__ void astore(int* p, int v) {
    __hip_atomic_store(p, v, __ATOMIC_RELAXED, __HIP_MEMORY_SCOPE_AGENT);
}

struct PParams {
    const float *s, *a, *s_next, *eps;
    const float *eWih, *eWhh, *ebih, *ebhh;
    const float *muW, *mub, *lvW, *lvb;
    const float *dWih, *dWhh, *dbih, *dbhh;
    const float *d1W, *d1b, *d2W, *d2b, *d3W, *d3b;
    int *bar;
    int *endv, *startv, *limitv;
    unsigned short *hencAb, *hencBb, *hdecAb, *hdecBb, *hf_bf;
    unsigned short *eWih_b, *eWhh_b, *dWih_b, *dWhh_b, *mlW_b, *xenc_b, *adec_b;
    unsigned short *d1Wb, *d2Wb, *d3Wb;
    unsigned short *y1b, *y2b;      // pipelined head scratch (dbuf per group)
    float *loss;
};

// ---------------------------------------------------------------- h-tile stage
// 32 rows (permuted) x 1024 cols bf16 (64 KB): 16 x 16B loads per thread.
__device__ __forceinline__ void stage_h32p(const unsigned short* __restrict__ src,
                                           const int* __restrict__ sperm,
                                           unsigned short* hstage, int tid) {
    i32x4 v[16];
    const int p = tid >> 7, col = (tid & 127) * 8;
    #pragma unroll
    for (int k = 0; k < 16; ++k) {
        const int row = sperm[p + 2 * k];           // physical sample id
        v[k] = ldg16(src + (size_t)row * LL + col);
    }
    asm volatile("s_waitcnt vmcnt(0)" ::: "memory");
    #pragma unroll
    for (int k = 0; k < 16; ++k)
        *(i32x4*)&hstage[(p + 2 * k) * HRS + col] = v[k];
}

// ---------------------------------------------------------------- barriers
// Global (phase 0 only): bar[g8*16] 8 class counters (32 each); [128] master;
// [132] broken; [144+b*16] per-block flags.
__device__ void gbar_global(int* bar, int bid, int tid, int gen) {
    __syncthreads();
    if (tid == 0) {
        if (aload(bar + 132) == 0) {
            const int g8 = bid & 7;
            int pos = __hip_atomic_fetch_add(bar + g8 * 16, 1, __ATOMIC_RELAXED, __HIP_MEMORY_SCOPE_AGENT);
            if (pos + 1 == (NBLK / 8) * gen) {
                int mp = __hip_atomic_fetch_add(bar + 128, 1, __ATOMIC_RELAXED, __HIP_MEMORY_SCOPE_AGENT);
                if (mp + 1 == 8 * gen) {
                    for (int b = 0; b < NBLK; ++b)
                        astore(bar + 144 + b * 16, gen);
                }
            }
            int it = 0;
            while (aload(bar + 144 + bid * 16) < gen) {
                __builtin_amdgcn_s_sleep(1);
                if (++it > 4000000) { astore(bar + 132, 1); break; }
            }
        }
    }
    __syncthreads();
}

// Group per-step barrier (r3 mechanics, best measured): gb[0,16,32,48] 4
// sub-counters (16 blocks each of 64); gb[64] master; gb[80] flag. Monotone.
__device__ void gbar_group(int* gb, int* brk, int lbid, int tid, int gen, int* sbrk) {
    asm volatile("s_waitcnt vmcnt(0)" ::: "memory");   // drain this wave's stores
    __syncthreads();
    if (tid == 0) {
        const int s = lbid & 3;
        int pos = __hip_atomic_fetch_add(gb + s * 16, 1, __ATOMIC_RELAXED, __HIP_MEMORY_SCOPE_AGENT);
        if (pos + 1 == 16 * gen) {
            int mp = __hip_atomic_fetch_add(gb + 64, 1, __ATOMIC_RELAXED, __HIP_MEMORY_SCOPE_AGENT);
            if (mp + 1 == 4 * gen)
                astore(gb + 80, gen);
        }
        if (*sbrk == 0) {
            int it = 0;
            while (aload(gb + 80) < gen) {
                __builtin_amdgcn_s_sleep(1);
                if (((++it) & 2047) == 0) {
                    if (aload(brk)) { *sbrk = 1; break; }
                    if (it > 2000000) { astore(brk, 1); *sbrk = 1; break; }
                }
            }
        }
    }
    __syncthreads();
}

// ---------------------------------------------------------------- init (separate launch)
__global__ void init_kernel(int* bar, float* loss) {
    for (int i = threadIdx.x; i < 5632; i += 256) bar[i] = 0;
    if (threadIdx.x == 0) loss[0] = 0.0f;
}

// ---------------------------------------------------------------- GRU step matmul tile
// Per group: 64 blocks x 16 j-cols (3 gates), 32 samples (permuted via sperm).
// trb = transpose scratch in shu (NOT hstage: y1 reads full hstage afterwards).
template<int XK, bool IS_DEC>
__device__ void gru_tile(const int* __restrict__ sperm, const int jb, const int tid,
    const unsigned short* __restrict__ h_bf, unsigned short* __restrict__ ho_bf,
    const unsigned short* __restrict__ Whh_b, const unsigned short* __restrict__ Wih_b,
    const unsigned short* __restrict__ x_bf,
    const float* __restrict__ bih, const float* __restrict__ bhh,
    const int* __restrict__ endv, unsigned short* __restrict__ hf_bf,
    int t, f32x4 (&red)[2][4][64], unsigned short* hstage, unsigned short* trb,
    f32x4& hold)
{
    const int lane = tid & 63, w = tid >> 6;
    const int nh = w & 1, kh = w >> 1;
    const int m = lane & 15, quad = lane >> 4;
    const int jcol = jb + m;

    stage_h32p(h_bf, sperm, hstage, tid);
    __syncthreads();

    f32x4 accr{}, accz{}, acchn{}, accxn{};

    {   // hidden: K = 1024, 32 chunks, split 16/16 across kh; A from LDS
        const int arow = (nh * 16 + m) * HRS + quad * 8;
        const unsigned short* brp = Whh_b + (size_t)(0 * LL + jcol) * LL + quad * 8;
        const unsigned short* bzp = Whh_b + (size_t)(1 * LL + jcol) * LL + quad * 8;
        const unsigned short* bnp = Whh_b + (size_t)(2 * LL + jcol) * LL + quad * 8;
        #pragma unroll 4
        for (int c = kh * 16; c < kh * 16 + 16; ++c) {
            const int k0 = c * 32;
            bf16x8 av = *(const bf16x8*)&hstage[arow + k0];
            bf16x8 br = *(const bf16x8*)(brp + k0);
            bf16x8 bz = *(const bf16x8*)(bzp + k0);
            bf16x8 bn = *(const bf16x8*)(bnp + k0);
            accr  = __builtin_amdgcn_mfma_f32_16x16x32_bf16(av, br, accr, 0, 0, 0);
            accz  = __builtin_amdgcn_mfma_f32_16x16x32_bf16(av, bz, accz, 0, 0, 0);
            acchn = __builtin_amdgcn_mfma_f32_16x16x32_bf16(av, bn, acchn, 0, 0, 0);
        }
    }
    {   // input: K = XK (enc 160, dec 32); read-only -> plain L1/L2-cached loads
        const int XC = XK / 32, XC0 = (XC + 1) / 2;
        const size_t xstride = IS_DEC ? (size_t)(50 * AA) : (size_t)(TT * (SS + AA));
        const int nphys = sperm[nh * 16 + m];
        const unsigned short* xp  = x_bf + (size_t)nphys * xstride + (size_t)t * XK + quad * 8;
        const unsigned short* brp = Wih_b + (size_t)(0 * LL + jcol) * XK + quad * 8;
        const unsigned short* bzp = Wih_b + (size_t)(1 * LL + jcol) * XK + quad * 8;
        const unsigned short* bnp = Wih_b + (size_t)(2 * LL + jcol) * XK + quad * 8;
        #pragma unroll
        for (int c = (kh ? XC0 : 0); c < (kh ? XC : XC0); ++c) {
            const int k0 = c * 32;
            bf16x8 av = *(const bf16x8*)(xp + k0);
            bf16x8 br = *(const bf16x8*)(brp + k0);
            bf16x8 bz = *(const bf16x8*)(bzp + k0);
            bf16x8 bn = *(const bf16x8*)(bnp + k0);
            accr  = __builtin_amdgcn_mfma_f32_16x16x32_bf16(av, br, accr, 0, 0, 0);
            accz  = __builtin_amdgcn_mfma_f32_16x16x32_bf16(av, bz, accz, 0, 0, 0);
            accxn = __builtin_amdgcn_mfma_f32_16x16x32_bf16(av, bn, accxn, 0, 0, 0);
        }
    }
    if (kh == 1) {
        red[nh][0][lane] = accr;  red[nh][1][lane] = accz;
        red[nh][2][lane] = acchn; red[nh][3][lane] = accxn;
    }
    __syncthreads();
    if (kh == 0) {
        accr  += red[nh][0][lane];  accz  += red[nh][1][lane];
        acchn += red[nh][2][lane];  accxn += red[nh][3][lane];
        const float br_  = bih[jcol] + bhh[jcol];
        const float bz_  = bih[LL + jcol] + bhh[LL + jcol];
        const float bxn_ = bih[2 * LL + jcol];
        const float bhn_ = bhh[2 * LL + jcol];
        unsigned short* tr = trb + nh * (16 * 24);       // wave-private transpose scratch
        #pragma unroll
        for (int i = 0; i < 4; ++i) {
            const int n = sperm[nh * 16 + quad * 4 + i]; // C layout: row=quad*4+i, col=m
            float r = sigmoidf_(accr[i] + br_);
            float z = sigmoidf_(accz[i] + bz_);
            float g = tanhf(accxn[i] + bxn_ + r * (acchn[i] + bhn_));
            float hn = (1.0f - z) * g + z * hold[i];
            hold[i] = hn;
            unsigned short hb = f2bf(hn);
            tr[(quad * 4 + i) * 24 + m] = hb;            // LDS transpose (wave-lockstep)
            if (!IS_DEC) { if (endv[n] == t) st2(hf_bf + (size_t)n * LL + jcol, hb); }
        }
        // coalesced 16B n-major stores: lanes 0..31 each store 8 bf16
        if (lane < 32) {
            const int nl = lane >> 1, jh = lane & 1;
            bf16x8 vv = *(const bf16x8*)&tr[nl * 24 + jh * 8];
            stg16(ho_bf + (size_t)sperm[nh * 16 + nl] * LL + jb + jh * 8, vv);
        }
    }
}

// ---------------------------------------------------------------- reparametrize tile
__device__ void emb_tile(const PParams& P, const int* __restrict__ sperm, const int jb,
                         const int tid, f32x4 (&red)[2][4][64], unsigned short* hstage,
                         unsigned short* trb, f32x4& hold)
{
    const int lane = tid & 63, w = tid >> 6;
    const int nh = w & 1, kh = w >> 1;
    const int m = lane & 15, quad = lane >> 4;
    const int jcol = jb + m;

    stage_h32p(P.hf_bf, sperm, hstage, tid);
    __syncthreads();

    f32x4 accm{}, accl{};
    const int arow = (nh * 16 + m) * HRS + quad * 8;
    const unsigned short* bmp = P.mlW_b + (size_t)jcol * LL + quad * 8;
    const unsigned short* blp = P.mlW_b + (size_t)(LL + jcol) * LL + quad * 8;
    #pragma unroll 4
    for (int c = kh * 16; c < kh * 16 + 16; ++c) {
        const int k0 = c * 32;
        bf16x8 av = *(const bf16x8*)&hstage[arow + k0];
        bf16x8 bm = *(const bf16x8*)(bmp + k0);
        bf16x8 bl = *(const bf16x8*)(blp + k0);
        accm = __builtin_amdgcn_mfma_f32_16x16x32_bf16(av, bm, accm, 0, 0, 0);
        accl = __builtin_amdgcn_mfma_f32_16x16x32_bf16(av, bl, accl, 0, 0, 0);
    }
    if (kh == 1) { red[nh][0][lane] = accm; red[nh][1][lane] = accl; }
    __syncthreads();
    if (kh == 0) {
        accm += red[nh][0][lane]; accl += red[nh][1][lane];
        unsigned short* tr = trb + nh * (16 * 24);
        #pragma unroll
        for (int i = 0; i < 4; ++i) {
            const int n = sperm[nh * 16 + quad * 4 + i];
            float mu = accm[i] + P.mub[jcol];
            float lv = accl[i] + P.lvb[jcol];
            float e = mu + expf(0.5f * lv) * P.eps[(size_t)n * LL + jcol];
            hold[i] = e;
            tr[(quad * 4 + i) * 24 + m] = f2bf(e);
        }
        if (lane < 32) {
            const int nl = lane >> 1, jh = lane & 1;
            bf16x8 vv = *(const bf16x8*)&tr[nl * 24 + jh * 8];
            stg16(P.hdecAb + (size_t)sperm[nh * 16 + nl] * LL + jb + jh * 8, vv);
        }
    }
}

// ---------------------------------------------------------------- pipelined head
// y1: block lbid=48+t owns tile t (r=t&1,c=t>>1) of y1[32][128]; A = own hstage.
__device__ void y1_tile(const PParams& P, int t, int tid,
                        const unsigned short* __restrict__ hstage,
                        unsigned short* __restrict__ y1cur)
{
    if (tid >= 64) return;
    const int m16 = tid & 15, quad = tid >> 4;
    const int rb = (t & 1) * 16, cb = (t >> 1) * 16;
    f32x4 acc{};
    const int abase = (rb + m16) * HRS + quad * 8;
    const unsigned short* bp = P.d1Wb + (size_t)(cb + m16) * LL + quad * 8;
    #pragma unroll 4
    for (int ch = 0; ch < 32; ++ch) {
        bf16x8 av = *(const bf16x8*)&hstage[abase + ch * 32];
        bf16x8 bv = *(const bf16x8*)(bp + ch * 32);
        acc = __builtin_amdgcn_mfma_f32_16x16x32_bf16(av, bv, acc, 0, 0, 0);
    }
    const float b = P.d1b[cb + m16];
    #pragma unroll
    for (int i = 0; i < 4; ++i)
        st2(y1cur + (rb + quad * 4 + i) * 128 + cb + m16, f2bf(fmaxf(acc[i] + b, 0.0f)));
}
// y2: block lbid=32+t owns tile t of y2[32][64]; A = y1prev (global, K=128).
__device__ void y2_tile(const PParams& P, int t, int tid,
                        const unsigned short* __restrict__ y1prev,
                        unsigned short* __restrict__ y2cur)
{
    if (tid >= 64) return;
    const int m16 = tid & 15, quad = tid >> 4;
    const int rb = (t & 1) * 16, cb = (t >> 1) * 16;
    i32x4 a4[4];
    #pragma unroll
    for (int ch = 0; ch < 4; ++ch)
        a4[ch] = ldg16(y1prev + (size_t)(rb + m16) * 128 + ch * 32 + quad * 8);
    asm volatile("s_waitcnt vmcnt(0)" ::: "memory");
    f32x4 acc{};
    #pragma unroll
    for (int ch = 0; ch < 4; ++ch) {
        union { i32x4 i; bf16x8 h; } u; u.i = a4[ch];
        bf16x8 bv = *(const bf16x8*)(P.d2Wb + (size_t)(cb + m16) * 128 + ch * 32 + quad * 8);
        acc = __builtin_amdgcn_mfma_f32_16x16x32_bf16(u.h, bv, acc, 0, 0, 0);
    }
    const float b = P.d2b[cb + m16];
    #pragma unroll
    for (int i = 0; i < 4; ++i)
        st2(y2cur + (rb + quad * 4 + i) * 64 + cb + m16, f2bf(fmaxf(acc[i] + b, 0.0f)));
}
// y3 + masked L1: block lbid=t owns tile t of y3[32][128]; A = y2prev (K=64).
// Loss accumulated per-lane in lossacc; ONE atomicAdd after the loop.
__device__ void y3_loss(const PParams& P, const int* __restrict__ sperm, int t, int tid,
                        const unsigned short* __restrict__ y2prev, int ti, float& lossacc)
{
    if (tid >= 64) return;
    const int m16 = tid & 15, quad = tid >> 4;
    const int rb = (t & 1) * 16, cb = (t >> 1) * 16;
    i32x4 a2[2];
    #pragma unroll
    for (int ch = 0; ch < 2; ++ch)
        a2[ch] = ldg16(y2prev + (size_t)(rb + m16) * 64 + ch * 32 + quad * 8);
    asm volatile("s_waitcnt vmcnt(0)" ::: "memory");
    f32x4 acc{};
    #pragma unroll
    for (int ch = 0; ch < 2; ++ch) {
        union { i32x4 i; bf16x8 h; } u; u.i = a2[ch];
        bf16x8 bv = *(const bf16x8*)(P.d3Wb + (size_t)(cb + m16) * 64 + ch * 32 + quad * 8);
        acc = __builtin_amdgcn_mfma_f32_16x16x32_bf16(u.h, bv, acc, 0, 0, 0);
    }
    const int col = cb + m16;
    const float b = P.d3b[col];
    #pragma unroll
    for (int i = 0; i < 4; ++i) {
        const int n = sperm[rb + quad * 4 + i];
        if (ti < P.limitv[n]) {
            int trw = ti + P.startv[n]; if (trw >= TT) trw -= TT;
            float v = P.s_next[(size_t)n * TT * SS + (size_t)trw * SS + col];
            lossacc += fabsf(v - (acc[i] + b));
        }
    }
}

// ---------------------------------------------------------------- the persistent kernel
__global__ __launch_bounds__(256, 2)
void persist(PParams P)
{
    __shared__ __align__(16) unsigned short hstage[32 * HRS];   // 66176 B
    __shared__ __align__(16) char shu[9728];                    // red [0..8192) + tr [8192..9728)
    __shared__ int sperm[32];                                   // group's permuted sample ids
    __shared__ int mint, sME, sML, sbrk;
    f32x4 (&red)[2][4][64] = *(f32x4 (*)[2][4][64])(shu);
    unsigned short* trb = (unsigned short*)(shu + 8192);
    const int bid = blockIdx.x, tid = threadIdx.x;
    const int g = bid & 3, lbid = bid >> 2;    // group g; lbid 0..63 all matmul
    const int jb = lbid * 16;
    int* gb = P.bar + 4608 + g * 128;          // group barrier state (512 B apart)
    int* brk = P.bar + 132;

    // ================= phase 0: cast (plain stores), split detection, h0, adec
    {
        const long N0 = 3072L * 160, N1 = N0 + 3072L * 1024, N2 = N1 + 3072L * 32,
                   N3 = N2 + 3072L * 1024, N4 = N3 + 1048576L, N5 = N4 + 1048576L,
                   N6 = N5 + 128L * 100 * 160, N7 = N6 + 131072L, N8 = N7 + 8192L,
                   N9 = N8 + 8192L;
        for (long i = (long)bid * 256 + tid; i < N9; i += (long)NBLK * 256) {
            if (i < N0)      P.eWih_b[i]      = f2bf(P.eWih[i]);
            else if (i < N1) P.eWhh_b[i - N0] = f2bf(P.eWhh[i - N0]);
            else if (i < N2) P.dWih_b[i - N1] = f2bf(P.dWih[i - N1]);
            else if (i < N3) P.dWhh_b[i - N2] = f2bf(P.dWhh[i - N2]);
            else if (i < N4) P.mlW_b[i - N3]  = f2bf(P.muW[i - N3]);
            else if (i < N5) P.mlW_b[1048576L + (i - N4)] = f2bf(P.lvW[i - N4]);
            else if (i < N6) {
                long j = i - N5;                  // n*16000 + t*160 + k
                int  k = (int)(j % 160);
                long nt = j / 160;
                int  t = (int)(nt % 100), n = (int)(nt / 100);
                float v = (k < SS) ? P.s[(size_t)n * TT * SS + (size_t)t * SS + k]
                                   : P.a[(size_t)n * TT * AA + (size_t)t * AA + (k - SS)];
                P.xenc_b[j] = f2bf(v);
            }
            else if (i < N7) P.d1Wb[i - N6] = f2bf(P.d1W[i - N6]);
            else if (i < N8) P.d2Wb[i - N7] = f2bf(P.d2W[i - N7]);
            else             P.d3Wb[i - N8] = f2bf(P.d3W[i - N8]);
        }
    }
    if (bid < NN_) {
        const int n = bid;
        if (tid == 0) mint = TT - 1;
        __syncthreads();
        int t = tid + 1;
        if (t < TT && tid < 128) {
            const float* row = P.s + (size_t)n * TT * SS + (size_t)t * SS;
            bool allz = true;
            for (int i = 0; i < SS; ++i) { if (row[i] != 0.0f) { allz = false; break; } }
            if (allz) atomicMin(&mint, t);
        }
        __syncthreads();
        const int m = mint, st = m + 1;
        if (tid == 0) { P.endv[n] = m - 1; P.startv[n] = st; P.limitv[n] = TT - 1 - m; }
        for (int idx = tid; idx < LL; idx += 256)
            P.hencAb[(size_t)n * LL + idx] = 0x3F80;   // bf16 1.0
        for (int idx = tid; idx < 50 * AA; idx += 256) {
            int i = idx >> 5, k = idx & 31;
            int tr = i + st; if (tr >= TT) tr -= TT;
            P.adec_b[(size_t)n * (50 * AA) + idx] =
                f2bf(P.a[(size_t)n * TT * AA + (size_t)tr * AA + k]);
        }
    }
    // one-time global heavy barrier: flush phase-0 plain stores, drop stale lines
    __syncthreads();
    if (tid == 0) __threadfence();
    gbar_global(P.bar, bid, tid, 1);
    if (tid == 0) __threadfence();
    __syncthreads();

    // ================= length-sorted permutation (identical in every block)
    {
        int* keys = (int*)shu;
        if (tid < 128) keys[tid] = P.endv[tid];
        if (tid == 0) sbrk = 0;
        __syncthreads();
        if (tid < 128) {
            const int k = keys[tid];
            int r = 0;
            for (int j = 0; j < 128; ++j) {
                const int kj = keys[j];
                r += (kj < k) | ((kj == k) & (j < tid));
            }
            if (r >= g * 32 && r < g * 32 + 32) sperm[r - g * 32] = tid;  // rank -> sample
        }
        __syncthreads();
    }

    // ================= group ME = max(end), ML = max(limit) over its 32 samples
    int ME, ML;
    {
        int lv = 0, ev = 0;
        if (tid < 32) { const int n = sperm[tid]; lv = P.limitv[n]; ev = P.endv[n]; }
        if (tid < 64) {
            for (int off = 16; off >= 1; off >>= 1) {
                lv = max(lv, __shfl_down(lv, off));
                ev = max(ev, __shfl_down(ev, off));
            }
            if (tid == 0) { sML = lv; sME = ev; }
        }
        __syncthreads();
        ML = sML; ME = sME;
        __syncthreads();
    }

    f32x4 hold = { 1.0f, 1.0f, 1.0f, 1.0f };   // enc h0 = ones (fp32 state lives here)
    float lossacc = 0.0f;                      // y3 blocks: running loss (one atomic at end)
    int ggen = 0;

    // ================= encoder: t = 0..ME_g (all 64 blocks, perfectly balanced)
    for (int t = 0; t <= ME; ++t) {
        const unsigned short* hib = (t & 1) ? P.hencBb : P.hencAb;
        unsigned short*       hob = (t & 1) ? P.hencAb : P.hencBb;
        gru_tile<160, false>(sperm, jb, tid, hib, hob,
                             P.eWhh_b, P.eWih_b, P.xenc_b, P.ebih, P.ebhh,
                             P.endv, P.hf_bf, t, red, hstage, trb, hold);
        gbar_group(gb, brk, lbid, tid, ++ggen, &sbrk);
    }

    // ================= reparametrize (deposits decoder h0 into hold regs)
    emb_tile(P, sperm, jb, tid, red, hstage, trb, hold);
    gbar_group(gb, brk, lbid, tid, ++ggen, &sbrk);

    // ================= decoder: i = 0..ML+2, pipelined head (depth 3)
    // step i: gru stages h_i, computes h_{i+1} (i<ML); y1(ti=i-1) from hstage;
    // y2(ti=i-2) from y1buf[prev]; y3+loss(ti=i-3) from y2buf[prev].
    unsigned short* y1g = P.y1b + (size_t)g * 2 * 32 * 128;
    unsigned short* y2g = P.y2b + (size_t)g * 2 * 32 * 64;
    for (int i = 0; i <= ML + 2; ++i) {
        const unsigned short* hib = (i & 1) ? P.hdecBb : P.hdecAb;
        if (i < ML) {
            unsigned short* hob = (i & 1) ? P.hdecAb : P.hdecBb;
            gru_tile<32, true>(sperm, jb, tid, hib, hob,
                               P.dWhh_b, P.dWih_b, P.adec_b, P.dbih, P.dbhh,
                               nullptr, nullptr, i, red, hstage, trb, hold);
        } else if (i == ML && lbid >= 48) {
            stage_h32p(hib, sperm, hstage, tid);   // h_ML for the last y1
            __syncthreads();
        }
        if (lbid >= 48) {
            if (i >= 1 && i <= ML)
                y1_tile(P, lbid - 48, tid, hstage, y1g + (size_t)(i & 1) * 32 * 128);
        } else if (lbid >= 32 && lbid < 40) {
            if (i >= 2 && i <= ML + 1)
                y2_tile(P, lbid - 32, tid, y1g + (size_t)((i & 1) ^ 1) * 32 * 128,
                        y2g + (size_t)(i & 1) * 32 * 64);
        } else if (lbid < 16) {
            if (i >= 3)
                y3_loss(P, sperm, lbid, tid, y2g + (size_t)((i & 1) ^ 1) * 32 * 64,
                        i - 3, lossacc);
        }
        gbar_group(gb, brk, lbid, tid, ++ggen, &sbrk);
    }

    // ================= loss: one wave-reduce + one atomicAdd per y3 block
    if (lbid < 16 && tid < 64) {
        for (int off = 32; off >= 1; off >>= 1) lossacc += __shfl_down(lossacc, off);
        if (tid == 0) atomicAdd(P.loss, lossacc);
    }
}

// ---------------------------------------------------------------- launch
extern "C" void kernel_launch(void* const* d_in, const int* in_sizes, int n_in,
                              void* d_out, int out_size, void* d_ws, size_t ws_size,
                              hipStream_t stream) {
    PParams P;
    P.s      = (const float*)d_in[0];
    P.a      = (const float*)d_in[1];
    P.s_next = (const float*)d_in[3];
    P.eps    = (const float*)d_in[4];
    P.eWih   = (const float*)d_in[5];
    P.eWhh   = (const float*)d_in[6];
    P.ebih   = (const float*)d_in[7];
    P.ebhh   = (const float*)d_in[8];
    P.muW    = (const float*)d_in[9];
    P.mub    = (const float*)d_in[10];
    P.lvW    = (const float*)d_in[11];
    P.lvb    = (const float*)d_in[12];
    // st1..st3 (13..18) dead code w.r.t. the loss
    P.dWih   = (const float*)d_in[19];
    P.dWhh   = (const float*)d_in[20];
    P.dbih   = (const float*)d_in[21];
    P.dbhh   = (const float*)d_in[22];
    P.d1W    = (const float*)d_in[23];
    P.d1b    = (const float*)d_in[24];
    P.d2W    = (const float*)d_in[25];
    P.d2b    = (const float*)d_in[26];
    P.d3W    = (const float*)d_in[27];
    P.d3b    = (const float*)d_in[28];
    P.loss   = (float*)d_out;

    char* p = (char*)d_ws;
    P.bar    = (int*)p;                    p += 24576;   // 6144 ints (barriers)
    P.endv   = (int*)p;                    p += 512;
    P.startv = (int*)p;                    p += 512;
    P.limitv = (int*)p;                    p += 512;
    p += 2560;                             // pad
    P.hencAb = (unsigned short*)p;         p += 128 * 1024 * 2;
    P.hencBb = (unsigned short*)p;         p += 128 * 1024 * 2;
    P.hdecAb = (unsigned short*)p;         p += 128 * 1024 * 2;
    P.hdecBb = (unsigned short*)p;         p += 128 * 1024 * 2;
    P.hf_bf  = (unsigned short*)p;         p += 128 * 1024 * 2;
    P.eWih_b = (unsigned short*)p;         p += 3072 * 160 * 2;
    P.eWhh_b = (unsigned short*)p;         p += 3072 * 1024 * 2;
    P.dWih_b = (unsigned short*)p;         p += 3072 * 32 * 2;
    P.dWhh_b = (unsigned short*)p;         p += 3072 * 1024 * 2;
    P.mlW_b  = (unsigned short*)p;         p += 2048 * 1024 * 2;
    P.xenc_b = (unsigned short*)p;         p += 128 * 100 * 160 * 2;
    P.adec_b = (unsigned short*)p;         p += 128 * 50 * 32 * 2;
    P.d1Wb   = (unsigned short*)p;         p += 128 * 1024 * 2;
    P.d2Wb   = (unsigned short*)p;         p += 64 * 128 * 2;
    P.d3Wb   = (unsigned short*)p;         p += 128 * 64 * 2;
    P.y1b    = (unsigned short*)p;         p += 4 * 2 * 32 * 128 * 2;   // 64 KB
    P.y2b    = (unsigned short*)p;         p += 4 * 2 * 32 * 64 * 2;    // 32 KB

    hipLaunchKernelGGL(init_kernel, dim3(1), dim3(256), 0, stream, P.bar, P.loss);
    hipLaunchKernelGGL(persist, dim3(NBLK), dim3(256), 0, stream, P);
}

// Round 13
// 1643.051 us; speedup vs baseline: 1.3621x; 1.0709x over previous
//
#include <hip/hip_runtime.h>
#include <math.h>

#define NN_ 128   // batch
#define TT  100   // time steps
#define SS  128   // state dim
#define AA  32    // action dim
#define LL  1024  // hidden (= Z)
#define NBLK 256  // 4 groups x 64 blocks -- 1 block/CU, zero stragglers (r9-proven)
#define HRS  1034 // LDS h-stage row stride (bf16): max 2-way bank aliasing (free)

// Round-13: revert to r9 (proven 1759us) + ONE safe lever: split barrier with
// the h-independent x-gate matmul (plain C++ loads, compiler-managed waits --
// no inline-asm->MFMA ordering hazard) computed in the arrive->wait window.
// r10's register-staged h (inline-asm loads feeding MFMA) is abandoned: it
// violates the asm-waitcnt/MFMA ordering rule and killed 3 rounds at runtime.
// All cross-block ops: __hip_atomic_* AGENT + asm "sc0 sc1" (proven classes).

typedef __attribute__((ext_vector_type(8))) short bf16x8;   // 8 bf16 in 4 VGPRs
typedef __attribute__((ext_vector_type(4))) float f32x4;
typedef __attribute__((ext_vector_type(4))) int   i32x4;

__device__ __forceinline__ float sigmoidf_(float x) { return 1.0f / (1.0f + expf(-x)); }
__device__ __forceinline__ unsigned short f2bf(float x) {
    union { float f; unsigned u; } v; v.f = x;
    return (unsigned short)((v.u + 0x7fffu + ((v.u >> 16) & 1u)) >> 16);   // RNE
}

// ---- coherent access helpers (system scope: sc0 sc1) -----------------------
__device__ __forceinline__ i32x4 ldg16(const unsigned short* p) {
    i32x4 r; asm volatile("global_load_dwordx4 %0, %1, off sc0 sc1"
                          : "=&v"(r) : "v"((unsigned long long)p));
    return r;   // caller must s_waitcnt vmcnt(0) before use (consumers are STORES)
}
__device__ __forceinline__ void stg16(unsigned short* p, bf16x8 v) {
    union { bf16x8 h; i32x4 i; } u; u.h = v;
    asm volatile("global_store_dwordx4 %0, %1, off sc0 sc1"
                 :: "v"((unsigned long long)p), "v"(u.i) : "memory");
}
__device__ __forceinline__ void st2(unsigned short* p, unsigned short v) {
    asm volatile("global_store_short %0, %1, off sc0 sc1"
                 :: "v"((unsigned long long)p), "v"((unsigned)v) : "memory");
}
__device__ __forceinline__ int aload(const int* p) {
    return __hip_atomic_load(p, __ATOMIC_RELAXED, __HIP_MEMORY_SCOPE_AGENT);
}
__device__ __forceinline__ void astore(int* p, int v) {
    __hip_atomic_store(p, v, __ATOMIC_RELAXED, __HIP_MEMORY_SCOPE_AGENT);
}

struct PParams {
    const float *s, *a, *s_next, *eps;
    const float *eWih, *eWhh, *ebih, *ebhh;
    const float *muW, *mub, *lvW, *lvb;
    const float *dWih, *dWhh, *dbih, *dbhh;
    const float *d1W, *d1b, *d2W, *d2b, *d3W, *d3b;
    int *bar;
    int *endv, *startv, *limitv;
    unsigned short *hencAb, *hencBb, *hdecAb, *hdecBb, *hf_bf;
    unsigned short *eWih_b, *eWhh_b, *dWih_b, *dWhh_b, *mlW_b, *xenc_b, *adec_b;
    unsigned short *d1Wb, *d2Wb, *d3Wb;
    unsigned short *y1b, *y2b;      // pipelined head scratch (dbuf per group)
    float *loss;
};

// ---------------------------------------------------------------- h-tile stage
// 32 rows (permuted) x 1024 cols bf16 (64 KB): 16 x 16B loads per thread.
// Consumers of v[] are LDS STORES -> ordered by the "memory"-clobbered waitcnt.
__device__ __forceinline__ void stage_h32p(const unsigned short* __restrict__ src,
                                           const int* __restrict__ sperm,
                                           unsigned short* hstage, int tid) {
    i32x4 v[16];
    const int p = tid >> 7, col = (tid & 127) * 8;
    #pragma unroll
    for (int k = 0; k < 16; ++k) {
        const int row = sperm[p + 2 * k];           // physical sample id
        v[k] = ldg16(src + (size_t)row * LL + col);
    }
    asm volatile("s_waitcnt vmcnt(0)" ::: "memory");
    #pragma unroll
    for (int k = 0; k < 16; ++k)
        *(i32x4*)&hstage[(p + 2 * k) * HRS + col] = v[k];
}

// ---------------------------------------------------------------- barriers
// Global (phase 0 only): bar[g8*16] 8 class counters (32 each); [128] master;
// [132] broken; [144+b*16] per-block flags.
__device__ void gbar_global(int* bar, int bid, int tid, int gen) {
    __syncthreads();
    if (tid == 0) {
        if (aload(bar + 132) == 0) {
            const int g8 = bid & 7;
            int pos = __hip_atomic_fetch_add(bar + g8 * 16, 1, __ATOMIC_RELAXED, __HIP_MEMORY_SCOPE_AGENT);
            if (pos + 1 == (NBLK / 8) * gen) {
                int mp = __hip_atomic_fetch_add(bar + 128, 1, __ATOMIC_RELAXED, __HIP_MEMORY_SCOPE_AGENT);
                if (mp + 1 == 8 * gen) {
                    for (int b = 0; b < NBLK; ++b)
                        astore(bar + 144 + b * 16, gen);
                }
            }
            int it = 0;
            while (aload(bar + 144 + bid * 16) < gen) {
                __builtin_amdgcn_s_sleep(1);
                if (++it > 4000000) { astore(bar + 132, 1); break; }
            }
        }
    }
    __syncthreads();
}

// Group per-step barrier, SPLIT (r9/r3 mechanics): gb[0,16,32,48] 4
// sub-counters (16 blocks each); gb[64] master; gb[80] flag. Monotone gens.
__device__ void gbar_arrive(int* gb, int lbid, int tid, int gen) {
    asm volatile("s_waitcnt vmcnt(0)" ::: "memory");   // drain this wave's stores
    __syncthreads();                                   // all waves drained
    if (tid == 0) {
        const int s = lbid & 3;
        int pos = __hip_atomic_fetch_add(gb + s * 16, 1, __ATOMIC_RELAXED, __HIP_MEMORY_SCOPE_AGENT);
        if (pos + 1 == 16 * gen) {
            int mp = __hip_atomic_fetch_add(gb + 64, 1, __ATOMIC_RELAXED, __HIP_MEMORY_SCOPE_AGENT);
            if (mp + 1 == 4 * gen)
                astore(gb + 80, gen);
        }
    }
}
__device__ void gbar_wait(int* gb, int* brk, int tid, int gen, int* sbrk) {
    if (tid == 0 && *sbrk == 0) {
        int it = 0;
        while (aload(gb + 80) < gen) {
            __builtin_amdgcn_s_sleep(1);
            if (((++it) & 2047) == 0) {
                if (aload(brk)) { *sbrk = 1; break; }
                if (it > 2000000) { astore(brk, 1); *sbrk = 1; break; }
            }
        }
    }
    __syncthreads();
}

// ---------------------------------------------------------------- init (separate launch)
__global__ void init_kernel(int* bar, float* loss) {
    for (int i = threadIdx.x; i < 5632; i += 256) bar[i] = 0;
    if (threadIdx.x == 0) loss[0] = 0.0f;
}

// ---------------------------------------------------------------- x-gate partials
// h-independent GRU part (x @ Wih for r,z,n), PLAIN C++ loads (compiler-safe).
// Computed in the arrive->wait window of the PREVIOUS barrier. kh chunk split
// identical to the old in-line input phase -> same per-gate sums.
template<int XK, bool IS_DEC>
__device__ __forceinline__ void x_part(const PParams& P, const int* __restrict__ sperm,
    const int jb, const int tid, int t, f32x4& axr, f32x4& axz, f32x4& axn)
{
    const int lane = tid & 63, w = tid >> 6;
    const int nh = w & 1, kh = w >> 1;
    const int m = lane & 15, quad = lane >> 4;
    const int jcol = jb + m;
    const unsigned short* Wih_b = IS_DEC ? P.dWih_b : P.eWih_b;
    const unsigned short* x_bf  = IS_DEC ? P.adec_b : P.xenc_b;
    f32x4 r{}, z{}, n{};
    const int XC = XK / 32, XC0 = (XC + 1) / 2;
    const size_t xstride = IS_DEC ? (size_t)(50 * AA) : (size_t)(TT * (SS + AA));
    const unsigned short* xp  = x_bf + (size_t)sperm[nh * 16 + m] * xstride + (size_t)t * XK + quad * 8;
    const unsigned short* brp = Wih_b + (size_t)(0 * LL + jcol) * XK + quad * 8;
    const unsigned short* bzp = Wih_b + (size_t)(1 * LL + jcol) * XK + quad * 8;
    const unsigned short* bnp = Wih_b + (size_t)(2 * LL + jcol) * XK + quad * 8;
    #pragma unroll
    for (int c = (kh ? XC0 : 0); c < (kh ? XC : XC0); ++c) {
        const int k0 = c * 32;
        bf16x8 av = *(const bf16x8*)(xp + k0);
        bf16x8 br = *(const bf16x8*)(brp + k0);
        bf16x8 bz = *(const bf16x8*)(bzp + k0);
        bf16x8 bn = *(const bf16x8*)(bnp + k0);
        r = __builtin_amdgcn_mfma_f32_16x16x32_bf16(av, br, r, 0, 0, 0);
        z = __builtin_amdgcn_mfma_f32_16x16x32_bf16(av, bz, z, 0, 0, 0);
        n = __builtin_amdgcn_mfma_f32_16x16x32_bf16(av, bn, n, 0, 0, 0);
    }
    axr = r; axz = z; axn = n;
}

// ---------------------------------------------------------------- GRU step matmul tile
// r9 gru_tile minus the input phase: accumulators seeded from x_part partials.
// h staged via LDS (store-ordered, compiler-safe). trb = transpose scratch.
template<bool IS_DEC>
__device__ void gru_tile(const PParams& P, const int* __restrict__ sperm, const int jb,
    const int tid, const unsigned short* __restrict__ h_bf,
    unsigned short* __restrict__ ho_bf, const unsigned short* __restrict__ Whh_b,
    const float* __restrict__ bih, const float* __restrict__ bhh, int t,
    f32x4 (&red)[2][4][64], unsigned short* hstage, unsigned short* trb, f32x4& hold,
    const f32x4 axr, const f32x4 axz, const f32x4 axn)
{
    const int lane = tid & 63, w = tid >> 6;
    const int nh = w & 1, kh = w >> 1;
    const int m = lane & 15, quad = lane >> 4;
    const int jcol = jb + m;

    stage_h32p(h_bf, sperm, hstage, tid);
    __syncthreads();

    f32x4 accr = axr, accz = axz, acchn{}, accxn = axn;

    {   // hidden: K = 1024, 32 chunks, split 16/16 across kh; A from LDS
        const int arow = (nh * 16 + m) * HRS + quad * 8;
        const unsigned short* brp = Whh_b + (size_t)(0 * LL + jcol) * LL + quad * 8;
        const unsigned short* bzp = Whh_b + (size_t)(1 * LL + jcol) * LL + quad * 8;
        const unsigned short* bnp = Whh_b + (size_t)(2 * LL + jcol) * LL + quad * 8;
        #pragma unroll 4
        for (int c = kh * 16; c < kh * 16 + 16; ++c) {
            const int k0 = c * 32;
            bf16x8 av = *(const bf16x8*)&hstage[arow + k0];
            bf16x8 br = *(const bf16x8*)(brp + k0);
            bf16x8 bz = *(const bf16x8*)(bzp + k0);
            bf16x8 bn = *(const bf16x8*)(bnp + k0);
            accr  = __builtin_amdgcn_mfma_f32_16x16x32_bf16(av, br, accr, 0, 0, 0);
            accz  = __builtin_amdgcn_mfma_f32_16x16x32_bf16(av, bz, accz, 0, 0, 0);
            acchn = __builtin_amdgcn_mfma_f32_16x16x32_bf16(av, bn, acchn, 0, 0, 0);
        }
    }
    if (kh == 1) {
        red[nh][0][lane] = accr;  red[nh][1][lane] = accz;
        red[nh][2][lane] = acchn; red[nh][3][lane] = accxn;
    }
    __syncthreads();
    if (kh == 0) {
        accr  += red[nh][0][lane];  accz  += red[nh][1][lane];
        acchn += red[nh][2][lane];  accxn += red[nh][3][lane];
        const float br_  = bih[jcol] + bhh[jcol];
        const float bz_  = bih[LL + jcol] + bhh[LL + jcol];
        const float bxn_ = bih[2 * LL + jcol];
        const float bhn_ = bhh[2 * LL + jcol];
        unsigned short* tr = trb + nh * (16 * 24);       // wave-private transpose scratch
        #pragma unroll
        for (int i = 0; i < 4; ++i) {
            const int n = sperm[nh * 16 + quad * 4 + i]; // C layout: row=quad*4+i, col=m
            float r = sigmoidf_(accr[i] + br_);
            float z = sigmoidf_(accz[i] + bz_);
            float g = tanhf(accxn[i] + bxn_ + r * (acchn[i] + bhn_));
            float hn = (1.0f - z) * g + z * hold[i];
            hold[i] = hn;
            unsigned short hb = f2bf(hn);
            tr[(quad * 4 + i) * 24 + m] = hb;            // LDS transpose (wave-lockstep)
            if (!IS_DEC) { if (P.endv[n] == t) st2(P.hf_bf + (size_t)n * LL + jcol, hb); }
        }
        // coalesced 16B n-major stores: lanes 0..31 each store 8 bf16
        if (lane < 32) {
            const int nl = lane >> 1, jh = lane & 1;
            bf16x8 vv = *(const bf16x8*)&tr[nl * 24 + jh * 8];
            stg16(ho_bf + (size_t)sperm[nh * 16 + nl] * LL + jb + jh * 8, vv);
        }
    }
}

// ---------------------------------------------------------------- reparametrize tile
__device__ void emb_tile(const PParams& P, const int* __restrict__ sperm, const int jb,
                         const int tid, f32x4 (&red)[2][4][64], unsigned short* hstage,
                         unsigned short* trb, f32x4& hold)
{
    const int lane = tid & 63, w = tid >> 6;
    const int nh = w & 1, kh = w >> 1;
    const int m = lane & 15, quad = lane >> 4;
    const int jcol = jb + m;

    stage_h32p(P.hf_bf, sperm, hstage, tid);
    __syncthreads();

    f32x4 accm{}, accl{};
    const int arow = (nh * 16 + m) * HRS + quad * 8;
    const unsigned short* bmp = P.mlW_b + (size_t)jcol * LL + quad * 8;
    const unsigned short* blp = P.mlW_b + (size_t)(LL + jcol) * LL + quad * 8;
    #pragma unroll 4
    for (int c = kh * 16; c < kh * 16 + 16; ++c) {
        const int k0 = c * 32;
        bf16x8 av = *(const bf16x8*)&hstage[arow + k0];
        bf16x8 bm = *(const bf16x8*)(bmp + k0);
        bf16x8 bl = *(const bf16x8*)(blp + k0);
        accm = __builtin_amdgcn_mfma_f32_16x16x32_bf16(av, bm, accm, 0, 0, 0);
        accl = __builtin_amdgcn_mfma_f32_16x16x32_bf16(av, bl, accl, 0, 0, 0);
    }
    if (kh == 1) { red[nh][0][lane] = accm; red[nh][1][lane] = accl; }
    __syncthreads();
    if (kh == 0) {
        accm += red[nh][0][lane]; accl += red[nh][1][lane];
        unsigned short* tr = trb + nh * (16 * 24);
        #pragma unroll
        for (int i = 0; i < 4; ++i) {
            const int n = sperm[nh * 16 + quad * 4 + i];
            float mu = accm[i] + P.mub[jcol];
            float lv = accl[i] + P.lvb[jcol];
            float e = mu + expf(0.5f * lv) * P.eps[(size_t)n * LL + jcol];
            hold[i] = e;
            tr[(quad * 4 + i) * 24 + m] = f2bf(e);
        }
        if (lane < 32) {
            const int nl = lane >> 1, jh = lane & 1;
            bf16x8 vv = *(const bf16x8*)&tr[nl * 24 + jh * 8];
            stg16(P.hdecAb + (size_t)sperm[nh * 16 + nl] * LL + jb + jh * 8, vv);
        }
    }
}

// ---------------------------------------------------------------- pipelined head (r9)
// y1: block lbid=48+t owns tile t (r=t&1,c=t>>1) of y1[32][128]; A = own hstage.
__device__ void y1_tile(const PParams& P, int t, int tid,
                        const unsigned short* __restrict__ hstage,
                        unsigned short* __restrict__ y1cur)
{
    if (tid >= 64) return;
    const int m16 = tid & 15, quad = tid >> 4;
    const int rb = (t & 1) * 16, cb = (t >> 1) * 16;
    f32x4 acc{};
    const int abase = (rb + m16) * HRS + quad * 8;
    const unsigned short* bp = P.d1Wb + (size_t)(cb + m16) * LL + quad * 8;
    #pragma unroll 4
    for (int ch = 0; ch < 32; ++ch) {
        bf16x8 av = *(const bf16x8*)&hstage[abase + ch * 32];
        bf16x8 bv = *(const bf16x8*)(bp + ch * 32);
        acc = __builtin_amdgcn_mfma_f32_16x16x32_bf16(av, bv, acc, 0, 0, 0);
    }
    const float b = P.d1b[cb + m16];
    #pragma unroll
    for (int i = 0; i < 4; ++i)
        st2(y1cur + (rb + quad * 4 + i) * 128 + cb + m16, f2bf(fmaxf(acc[i] + b, 0.0f)));
}
// y2: block lbid=32+t owns tile t of y2[32][64]; A = y1prev (global, K=128).
__device__ void y2_tile(const PParams& P, int t, int tid,
                        const unsigned short* __restrict__ y1prev,
                        unsigned short* __restrict__ y2cur)
{
    if (tid >= 64) return;
    const int m16 = tid & 15, quad = tid >> 4;
    const int rb = (t & 1) * 16, cb = (t >> 1) * 16;
    i32x4 a4[4];
    #pragma unroll
    for (int ch = 0; ch < 4; ++ch)
        a4[ch] = ldg16(y1prev + (size_t)(rb + m16) * 128 + ch * 32 + quad * 8);
    asm volatile("s_waitcnt vmcnt(0)" ::: "memory");
    __builtin_amdgcn_sched_barrier(0);     // pin MFMAs after the waitcnt (rule #18)
    f32x4 acc{};
    #pragma unroll
    for (int ch = 0; ch < 4; ++ch) {
        union { i32x4 i; bf16x8 h; } u; u.i = a4[ch];
        bf16x8 bv = *(const bf16x8*)(P.d2Wb + (size_t)(cb + m16) * 128 + ch * 32 + quad * 8);
        acc = __builtin_amdgcn_mfma_f32_16x16x32_bf16(u.h, bv, acc, 0, 0, 0);
    }
    const float b = P.d2b[cb + m16];
    #pragma unroll
    for (int i = 0; i < 4; ++i)
        st2(y2cur + (rb + quad * 4 + i) * 64 + cb + m16, f2bf(fmaxf(acc[i] + b, 0.0f)));
}
// y3 + masked L1: block lbid=t owns tile t; A = y2prev (K=64); loss in regs.
__device__ void y3_loss(const PParams& P, const int* __restrict__ sperm, int t, int tid,
                        const unsigned short* __restrict__ y2prev, int ti, float& lossacc)
{
    if (tid >= 64) return;
    const int m16 = tid & 15, quad = tid >> 4;
    const int rb = (t & 1) * 16, cb = (t >> 1) * 16;
    i32x4 a2[2];
    #pragma unroll
    for (int ch = 0; ch < 2; ++ch)
        a2[ch] = ldg16(y2prev + (size_t)(rb + m16) * 64 + ch * 32 + quad * 8);
    asm volatile("s_waitcnt vmcnt(0)" ::: "memory");
    __builtin_amdgcn_sched_barrier(0);     // pin MFMAs after the waitcnt (rule #18)
    f32x4 acc{};
    #pragma unroll
    for (int ch = 0; ch < 2; ++ch) {
        union { i32x4 i; bf16x8 h; } u; u.i = a2[ch];
        bf16x8 bv = *(const bf16x8*)(P.d3Wb + (size_t)(cb + m16) * 64 + ch * 32 + quad * 8);
        acc = __builtin_amdgcn_mfma_f32_16x16x32_bf16(u.h, bv, acc, 0, 0, 0);
    }
    const int col = cb + m16;
    const float b = P.d3b[col];
    #pragma unroll
    for (int i = 0; i < 4; ++i) {
        const int n = sperm[rb + quad * 4 + i];
        if (ti < P.limitv[n]) {
            int trw = ti + P.startv[n]; if (trw >= TT) trw -= TT;
            float v = P.s_next[(size_t)n * TT * SS + (size_t)trw * SS + col];
            lossacc += fabsf(v - (acc[i] + b));
        }
    }
}

// ---------------------------------------------------------------- the persistent kernel
__global__ __launch_bounds__(256, 2)
void persist(PParams P)
{
    __shared__ __align__(16) unsigned short hstage[32 * HRS];   // 66176 B
    __shared__ __align__(16) char shu[9728];                    // red [0..8192) + tr [8192..9728)
    __shared__ int sperm[32];                                   // group's permuted sample ids
    __shared__ int mint, sME, sML, sbrk;
    f32x4 (&red)[2][4][64] = *(f32x4 (*)[2][4][64])(shu);
    unsigned short* trb = (unsigned short*)(shu + 8192);
    const int bid = blockIdx.x, tid = threadIdx.x;
    const int g = bid & 3, lbid = bid >> 2;    // group g; lbid 0..63 all matmul
    const int jb = lbid * 16;
    int* gb = P.bar + 4608 + g * 128;          // group barrier state (512 B apart)
    int* brk = P.bar + 132;

    // ================= phase 0: cast (plain stores), split detection, h0, adec
    {
        const long N0 = 3072L * 160, N1 = N0 + 3072L * 1024, N2 = N1 + 3072L * 32,
                   N3 = N2 + 3072L * 1024, N4 = N3 + 1048576L, N5 = N4 + 1048576L,
                   N6 = N5 + 128L * 100 * 160, N7 = N6 + 131072L, N8 = N7 + 8192L,
                   N9 = N8 + 8192L;
        for (long i = (long)bid * 256 + tid; i < N9; i += (long)NBLK * 256) {
            if (i < N0)      P.eWih_b[i]      = f2bf(P.eWih[i]);
            else if (i < N1) P.eWhh_b[i - N0] = f2bf(P.eWhh[i - N0]);
            else if (i < N2) P.dWih_b[i - N1] = f2bf(P.dWih[i - N1]);
            else if (i < N3) P.dWhh_b[i - N2] = f2bf(P.dWhh[i - N2]);
            else if (i < N4) P.mlW_b[i - N3]  = f2bf(P.muW[i - N3]);
            else if (i < N5) P.mlW_b[1048576L + (i - N4)] = f2bf(P.lvW[i - N4]);
            else if (i < N6) {
                long j = i - N5;                  // n*16000 + t*160 + k
                int  k = (int)(j % 160);
                long nt = j / 160;
                int  t = (int)(nt % 100), n = (int)(nt / 100);
                float v = (k < SS) ? P.s[(size_t)n * TT * SS + (size_t)t * SS + k]
                                   : P.a[(size_t)n * TT * AA + (size_t)t * AA + (k - SS)];
                P.xenc_b[j] = f2bf(v);
            }
            else if (i < N7) P.d1Wb[i - N6] = f2bf(P.d1W[i - N6]);
            else if (i < N8) P.d2Wb[i - N7] = f2bf(P.d2W[i - N7]);
            else             P.d3Wb[i - N8] = f2bf(P.d3W[i - N8]);
        }
    }
    if (bid < NN_) {
        const int n = bid;
        if (tid == 0) mint = TT - 1;
        __syncthreads();
        int t = tid + 1;
        if (t < TT && tid < 128) {
            const float* row = P.s + (size_t)n * TT * SS + (size_t)t * SS;
            bool allz = true;
            for (int i = 0; i < SS; ++i) { if (row[i] != 0.0f) { allz = false; break; } }
            if (allz) atomicMin(&mint, t);
        }
        __syncthreads();
        const int m = mint, st = m + 1;
        if (tid == 0) { P.endv[n] = m - 1; P.startv[n] = st; P.limitv[n] = TT - 1 - m; }
        for (int idx = tid; idx < LL; idx += 256)
            P.hencAb[(size_t)n * LL + idx] = 0x3F80;   // bf16 1.0
        for (int idx = tid; idx < 50 * AA; idx += 256) {
            int i = idx >> 5, k = idx & 31;
            int tr = i + st; if (tr >= TT) tr -= TT;
            P.adec_b[(size_t)n * (50 * AA) + idx] =
                f2bf(P.a[(size_t)n * TT * AA + (size_t)tr * AA + k]);
        }
    }
    // one-time global heavy barrier: flush phase-0 plain stores, drop stale lines
    __syncthreads();
    if (tid == 0) __threadfence();
    gbar_global(P.bar, bid, tid, 1);
    if (tid == 0) __threadfence();
    __syncthreads();

    // ================= length-sorted permutation (identical in every block)
    {
        int* keys = (int*)shu;
        if (tid < 128) keys[tid] = P.endv[tid];
        if (tid == 0) sbrk = 0;
        __syncthreads();
        if (tid < 128) {
            const int k = keys[tid];
            int r = 0;
            for (int j = 0; j < 128; ++j) {
                const int kj = keys[j];
                r += (kj < k) | ((kj == k) & (j < tid));
            }
            if (r >= g * 32 && r < g * 32 + 32) sperm[r - g * 32] = tid;  // rank -> sample
        }
        __syncthreads();
    }

    // ================= group ME = max(end), ML = max(limit) over its 32 samples
    int ME, ML;
    {
        int lv = 0, ev = 0;
        if (tid < 32) { const int n = sperm[tid]; lv = P.limitv[n]; ev = P.endv[n]; }
        if (tid < 64) {
            for (int off = 16; off >= 1; off >>= 1) {
                lv = max(lv, __shfl_down(lv, off));
                ev = max(ev, __shfl_down(ev, off));
            }
            if (tid == 0) { sML = lv; sME = ev; }
        }
        __syncthreads();
        ML = sML; ME = sME;
        __syncthreads();
    }

    f32x4 hold = { 1.0f, 1.0f, 1.0f, 1.0f };   // enc h0 = ones (fp32 state lives here)
    f32x4 axr{}, axz{}, axn{};
    float lossacc = 0.0f;
    int ggen = 0;

    // ================= encoder: t = 0..ME (x-part of t+1 hidden under barrier)
    x_part<160, false>(P, sperm, jb, tid, 0, axr, axz, axn);
    for (int t = 0; t <= ME; ++t) {
        const unsigned short* hib = (t & 1) ? P.hencBb : P.hencAb;
        unsigned short*       hob = (t & 1) ? P.hencAb : P.hencBb;
        gru_tile<false>(P, sperm, jb, tid, hib, hob, P.eWhh_b, P.ebih, P.ebhh,
                        t, red, hstage, trb, hold, axr, axz, axn);
        ++ggen;
        gbar_arrive(gb, lbid, tid, ggen);
        if (t < ME) x_part<160, false>(P, sperm, jb, tid, t + 1, axr, axz, axn);
        gbar_wait(gb, brk, tid, ggen, &sbrk);
    }

    // ================= reparametrize (decoder x(0) hidden under its barrier)
    emb_tile(P, sperm, jb, tid, red, hstage, trb, hold);
    ++ggen;
    gbar_arrive(gb, lbid, tid, ggen);
    x_part<32, true>(P, sperm, jb, tid, 0, axr, axz, axn);
    gbar_wait(gb, brk, tid, ggen, &sbrk);

    // ================= decoder: i = 0..ML+2, pipelined head (depth 3, r9)
    unsigned short* y1g = P.y1b + (size_t)g * 2 * 32 * 128;
    unsigned short* y2g = P.y2b + (size_t)g * 2 * 32 * 64;
    for (int i = 0; i <= ML + 2; ++i) {
        const unsigned short* hib = (i & 1) ? P.hdecBb : P.hdecAb;
        if (i < ML) {
            unsigned short* hob = (i & 1) ? P.hdecAb : P.hdecBb;
            gru_tile<true>(P, sperm, jb, tid, hib, hob, P.dWhh_b, P.dbih, P.dbhh,
                           i, red, hstage, trb, hold, axr, axz, axn);
        } else if (i == ML && lbid >= 48) {
            stage_h32p(hib, sperm, hstage, tid);   // h_ML for the last y1
            __syncthreads();
        }
        if (lbid >= 48) {
            if (i >= 1 && i <= ML)
                y1_tile(P, lbid - 48, tid, hstage, y1g + (size_t)(i & 1) * 32 * 128);
        } else if (lbid >= 32 && lbid < 40) {
            if (i >= 2 && i <= ML + 1)
                y2_tile(P, lbid - 32, tid, y1g + (size_t)((i & 1) ^ 1) * 32 * 128,
                        y2g + (size_t)(i & 1) * 32 * 64);
        } else if (lbid < 16) {
            if (i >= 3)
                y3_loss(P, sperm, lbid, tid, y2g + (size_t)((i & 1) ^ 1) * 32 * 64,
                        i - 3, lossacc);
        }
        ++ggen;
        gbar_arrive(gb, lbid, tid, ggen);
        if (i + 1 < ML) x_part<32, true>(P, sperm, jb, tid, i + 1, axr, axz, axn);
        gbar_wait(gb, brk, tid, ggen, &sbrk);
    }

    // ================= loss: one wave-reduce + one atomicAdd per y3 block
    if (lbid < 16 && tid < 64) {
        for (int off = 32; off >= 1; off >>= 1) lossacc += __shfl_down(lossacc, off);
        if (tid == 0) atomicAdd(P.loss, lossacc);
    }
}

// ---------------------------------------------------------------- launch
extern "C" void kernel_launch(void* const* d_in, const int* in_sizes, int n_in,
                              void* d_out, int out_size, void* d_ws, size_t ws_size,
                              hipStream_t stream) {
    PParams P;
    P.s      = (const float*)d_in[0];
    P.a      = (const float*)d_in[1];
    P.s_next = (const float*)d_in[3];
    P.eps    = (const float*)d_in[4];
    P.eWih   = (const float*)d_in[5];
    P.eWhh   = (const float*)d_in[6];
    P.ebih   = (const float*)d_in[7];
    P.ebhh   = (const float*)d_in[8];
    P.muW    = (const float*)d_in[9];
    P.mub    = (const float*)d_in[10];
    P.lvW    = (const float*)d_in[11];
    P.lvb    = (const float*)d_in[12];
    // st1..st3 (13..18) dead code w.r.t. the loss
    P.dWih   = (const float*)d_in[19];
    P.dWhh   = (const float*)d_in[20];
    P.dbih   = (const float*)d_in[21];
    P.dbhh   = (const float*)d_in[22];
    P.d1W    = (const float*)d_in[23];
    P.d1b    = (const float*)d_in[24];
    P.d2W    = (const float*)d_in[25];
    P.d2b    = (const float*)d_in[26];
    P.d3W    = (const float*)d_in[27];
    P.d3b    = (const float*)d_in[28];
    P.loss   = (float*)d_out;

    char* p = (char*)d_ws;
    P.bar    = (int*)p;                    p += 24576;   // 6144 ints (barriers)
    P.endv   = (int*)p;                    p += 512;
    P.startv = (int*)p;                    p += 512;
    P.limitv = (int*)p;                    p += 512;
    p += 2560;                             // pad
    P.hencAb = (unsigned short*)p;         p += 128 * 1024 * 2;
    P.hencBb = (unsigned short*)p;         p += 128 * 1024 * 2;
    P.hdecAb = (unsigned short*)p;         p += 128 * 1024 * 2;
    P.hdecBb = (unsigned short*)p;         p += 128 * 1024 * 2;
    P.hf_bf  = (unsigned short*)p;         p += 128 * 1024 * 2;
    P.eWih_b = (unsigned short*)p;         p += 3072 * 160 * 2;
    P.eWhh_b = (unsigned short*)p;         p += 3072 * 1024 * 2;
    P.dWih_b = (unsigned short*)p;         p += 3072 * 32 * 2;
    P.dWhh_b = (unsigned short*)p;         p += 3072 * 1024 * 2;
    P.mlW_b  = (unsigned short*)p;         p += 2048 * 1024 * 2;
    P.xenc_b = (unsigned short*)p;         p += 128 * 100 * 160 * 2;
    P.adec_b = (unsigned short*)p;         p += 128 * 50 * 32 * 2;
    P.d1Wb   = (unsigned short*)p;         p += 128 * 1024 * 2;
    P.d2Wb   = (unsigned short*)p;         p += 64 * 128 * 2;
    P.d3Wb   = (unsigned short*)p;         p += 128 * 64 * 2;
    P.y1b    = (unsigned short*)p;         p += 4 * 2 * 32 * 128 * 2;   // 64 KB
    P.y2b    = (unsigned short*)p;         p += 4 * 2 * 32 * 64 * 2;    // 32 KB

    hipLaunchKernelGGL(init_kernel, dim3(1), dim3(256), 0, stream, P.bar, P.loss);
    hipLaunchKernelGGL(persist, dim3(NBLK), dim3(256), 0, stream, P);
}